// Round 5
// baseline (5808.678 us; speedup 1.0000x reference)
//
#include <hip/hip_runtime.h>
#include <hip/hip_fp16.h>

#define PLANE 262144   // 512*512
#define NC 21
#define NB 8
#define NPIX (NB*PLANE)

__device__ __forceinline__ float2 h2f(unsigned int u) {
  union { unsigned int u; __half2 h; } x; x.u = u;
  return __half22float2(x.h);
}
__device__ __forceinline__ unsigned int f2h(float a, float b) {
  union { unsigned int u; __half2 h; } x;
  x.h = __floats2half2_rn(a, b);
  return x.u;
}

// ---------------- prep: edge = exp(-|sobel(gray)|) ----------------
__global__ __launch_bounds__(256)
void k_edge(const float* __restrict__ img, __half* __restrict__ edge16) {
  int id = blockIdx.x*256 + threadIdx.x;
  int b = id >> 18;
  int rem = id & (PLANE-1);
  int y = rem >> 9, x = rem & 511;
  const float* ib = img + (size_t)b*3*PLANE;
  float g[3][3];
#pragma unroll
  for (int dy=0; dy<3; ++dy)
#pragma unroll
    for (int dx=0; dx<3; ++dx) {
      int yy = y+dy-1, xx = x+dx-1;
      float v = 0.f;
      if (yy>=0 && yy<512 && xx>=0 && xx<512) {
        int o = (yy<<9)|xx;
        v = 0.299f*ib[o] + 0.587f*ib[o+PLANE] + 0.114f*ib[o+2*PLANE];
      }
      g[dy][dx]=v;
    }
  float gxv = (g[0][2]-g[0][0]) + 2.f*(g[1][2]-g[1][0]) + (g[2][2]-g[2][0]);
  float gyv = (g[2][0]-g[0][0]) + 2.f*(g[2][1]-g[0][1]) + (g[2][2]-g[0][2]);
  float mag = sqrtf(gxv*gxv + gyv*gyv + 1e-6f);
  edge16[id] = __float2half(__expf(-mag));
}

// ---------------- prep: rnorm = 1/(avgpool3(edge)+1e-6) ----------------
__global__ __launch_bounds__(256)
void k_rnorm(const __half* __restrict__ edge16, float* __restrict__ rnorm) {
  int id = blockIdx.x*256 + threadIdx.x;
  int b = id >> 18;
  int rem = id & (PLANE-1);
  int y = rem >> 9, x = rem & 511;
  const __half* eb = edge16 + (size_t)b*PLANE;
  float s = 0.f;
#pragma unroll
  for (int dy=-1; dy<=1; ++dy)
#pragma unroll
    for (int dx=-1; dx<=1; ++dx) {
      int yy = y+dy, xx = x+dx;
      if (yy>=0 && yy<512 && xx>=0 && xx<512) s += __half2float(eb[(yy<<9)|xx]);
    }
  rnorm[id] = 1.f/(s*(1.f/9.f) + 1e-6f);
}

// ---------------- prep: compat == identity? ----------------
__global__ void k_flag(const float* __restrict__ compat, int* __restrict__ flag) {
  __shared__ int ok;
  if (threadIdx.x==0) ok = 1;
  __syncthreads();
  int bad = 0;
  for (int i = threadIdx.x; i < NC*NC; i += 256) {
    float exp = ((i/NC) == (i%NC)) ? 1.f : 0.f;
    if (compat[i] != exp) bad = 1;
  }
  if (bad) atomicAnd(&ok, 0);
  __syncthreads();
  if (threadIdx.x==0) flag[0] = ok;
}

// ---------------- prep: unary fp32 -> fp16 ----------------
__global__ __launch_bounds__(256)
void k_cvt(const float* __restrict__ u, __half* __restrict__ u16) {
  size_t q = (size_t)blockIdx.x*256 + threadIdx.x;
  float4 v = reinterpret_cast<const float4*>(u)[q];
  uint2 w; w.x = f2h(v.x, v.y); w.y = f2h(v.z, v.w);
  reinterpret_cast<uint2*>(u16)[q] = w;
}

// ---------------- Q0 = softmax(unary) -> fp16 ----------------
__global__ __launch_bounds__(256)
void k_softmax0(const float* __restrict__ unary, __half* __restrict__ Y) {
  int q = blockIdx.x*256 + threadIdx.x;           // quad id, [0, NPIX/4)
  int b = q >> 16;
  int rem = q & 65535;
  size_t base = (size_t)b*NC*(PLANE>>2) + rem;
  const float4* up = reinterpret_cast<const float4*>(unary);
  float v[NC][4];
  float mx0=-3e38f,mx1=-3e38f,mx2=-3e38f,mx3=-3e38f;
#pragma unroll
  for (int c=0;c<NC;++c) {
    float4 t = up[base + (size_t)c*(PLANE>>2)];
    v[c][0]=t.x; v[c][1]=t.y; v[c][2]=t.z; v[c][3]=t.w;
    mx0=fmaxf(mx0,t.x); mx1=fmaxf(mx1,t.y); mx2=fmaxf(mx2,t.z); mx3=fmaxf(mx3,t.w);
  }
  float s0=0,s1=0,s2=0,s3=0;
#pragma unroll
  for (int c=0;c<NC;++c) {
    float e0=__expf(v[c][0]-mx0), e1=__expf(v[c][1]-mx1);
    float e2=__expf(v[c][2]-mx2), e3=__expf(v[c][3]-mx3);
    v[c][0]=e0; v[c][1]=e1; v[c][2]=e2; v[c][3]=e3;
    s0+=e0; s1+=e1; s2+=e2; s3+=e3;
  }
  float r0=1.f/s0, r1=1.f/s1, r2=1.f/s2, r3=1.f/s3;
  uint2* yp = reinterpret_cast<uint2*>(Y);
#pragma unroll
  for (int c=0;c<NC;++c) {
    uint2 w; w.x=f2h(v[c][0]*r0, v[c][1]*r1); w.y=f2h(v[c][2]*r2, v[c][3]*r3);
    yp[base + (size_t)c*(PLANE>>2)] = w;
  }
}

// ---------------- fused CRF iteration ----------------
// R5: 4 phase-independent blocks/CU + u16 register prefetch.
// R4 post-mortem: FETCH is fully explained by cache-line granularity (staged
// 144B rows span 4 lines) -- NOT spills. Kernel is latency/overlap-bound:
// VALU ~23us, LDS ~15us, HBM floor ~110us, measured 275us @30% HBM. The
// 2 phase-locked blocks/CU leave HBM idle during compute phases. Now:
// tile 64x8, 256 threads, LDS 38KB -> 4 blocks/CU in staggered phases;
// u16 values prefetched into 21 regs before the barrier so phase 2 has no
// dependent global-load stall.

#define LOAD_U2(c, u0,u1) \
  float u0,u1; \
  if (U16) { float2 t_=h2f(upf[c]); u0=t_.x; u1=t_.y; } \
  else { float2 v_ = reinterpret_cast<const float2*>(uptr)[hbase + (size_t)(c)*ch]; \
    u0=v_.x; u1=v_.y; }

#define ACCUM_COMPAT2(c, a0,a1) \
  float a0=0.f,a1=0.f; \
  _Pragma("unroll") \
  for (int d=0; d<NC; ++d) { float cf_ = compat[(c)*NC+d]; \
    a0 += cf_*msgr[d][0]; a1 += cf_*msgr[d][1]; }

#define CROW 72            // LDS row stride (halves) == staged cols
#define TROWS 12           // staged rows (8 tile + 4 halo)
#define CTILE (TROWS*CROW) // halves per channel tile

template<bool U16, bool OUTF32>
__global__ __launch_bounds__(256, 4)
void k_iter(const __half* __restrict__ Qin,
            void* __restrict__ Qout,
            const void* __restrict__ uptr,
            const __half* __restrict__ edge16,
            const float* __restrict__ rnorm,
            const float* __restrict__ swp,
            const float* __restrict__ bwp,
            const float* __restrict__ compat,
            const int* __restrict__ flag)
{
  __shared__ __half qt21[NC*CTILE];   // 21 x 12 x 72 halves = 36288 B
  __shared__ __half et[CTILE];        // 12 x 72 halves      =  1728 B

  const int tid = threadIdx.x;
  const int tx = tid & 31;        // 32 threads across 64 px, 2 px each
  const int ty = tid >> 5;        // 8 rows
  const int x0 = blockIdx.x << 6;
  const int y0 = blockIdx.y << 3;
  const int b  = blockIdx.z;

  // ---- staging slot: 12 rows x 18 uint2 (4 halves) = 216 slots ----
  const int slot = tid;
  const int sr = slot / 18;
  const int si = slot - sr*18;
  const int sy = y0 - 2 + sr;                 // rows y0-2 .. y0+9
  const int sx = x0 - 4 + (si<<2);            // cols x0-4 .. x0+67, step 4
  const bool sact = (slot < 216);
  const bool sval = sact && (sy>=0) && (sy<512) && (sx>=0) && (sx<512);
  const int  goff = (sy<<9) + sx;             // halves into plane (use iff sval)
  const int  loff = sr*CROW + (si<<2);        // halves into tile

  const int gy  = y0 + ty;
  const int gx  = x0 + (tx<<1);
  const int pix = (gy<<9) | gx;

  // early independent loads (overlap with staging latency)
  const float2 rn = *reinterpret_cast<const float2*>(rnorm + (size_t)b*PLANE + pix);
  const float sw  = fmaxf(swp[0], 0.f);
  const float bw  = fmaxf(bwp[0], 0.f);
  const int fl = flag[0];

  const size_t hbase = (((size_t)b*NC*PLANE) + (size_t)pix) >> 1;  // half2 / float2 units
  const size_t ch = PLANE >> 1;

  // prefetch phase-2 unary values into registers (U16 path): 21 loads issued
  // here stay in flight under the whole compute phase.
  unsigned int upf[NC];
  if (U16) {
#pragma unroll
    for (int c=0;c<NC;++c)
      upf[c] = reinterpret_cast<const unsigned int*>(uptr)[hbase + (size_t)c*ch];
  }

  // ---- memory phase: edge tile + ALL 21 channel tiles, one barrier ----
  {
    const __half* ep = edge16 + (size_t)b*PLANE;
    uint2 w = make_uint2(0u, 0u);
    if (sval) w = *reinterpret_cast<const uint2*>(ep + goff);
    if (sact) *reinterpret_cast<uint2*>(et + loff) = w;
  }
  const __half* qb = Qin + (size_t)b*NC*PLANE;
#pragma unroll
  for (int c=0;c<NC;++c) {
    uint2 w = make_uint2(0u, 0u);
    if (sval) w = *reinterpret_cast<const uint2*>(qb + (size_t)c*PLANE + goff);
    if (sact) *reinterpret_cast<uint2*>(qt21 + c*CTILE + loff) = w;
  }
  __syncthreads();

  const float csw = sw * 0.04f;          // sw/25
  const float b9  = bw * (1.f/9.f);      // bw/9
  const float cb0 = b9*rn.x, cb1 = b9*rn.y;

  const int lx2 = (tx<<1) + 2;           // LDS col of gx-2 (staged region shift)

  // hoist edge window into registers once (channel-invariant):
  // rows ty+1..ty+3, global cols gx-1..gx+2 = staged cols lx2+1..lx2+4
  float ew[3][4];
#pragma unroll
  for (int dy=0;dy<3;++dy) {
    const unsigned int* erow = reinterpret_cast<const unsigned int*>(et + (ty+1+dy)*CROW + lx2);
    float2 e0 = h2f(erow[0]);
    float2 e1 = h2f(erow[1]);
    float2 e2 = h2f(erow[2]);
    ew[dy][0]=e0.y; ew[dy][1]=e1.x; ew[dy][2]=e1.y; ew[dy][3]=e2.x;
  }

  // ---- compute phase: pure LDS reads, no global traffic ----
  float msgr[NC][2];
  const __half* qrow0 = qt21 + ty*CROW + lx2;

#pragma unroll
  for (int c=0;c<NC;++c) {
    float cs0=0,cs1=0,cs2=0,cs3=0,cs4=0,cs5=0;
    float ce0=0,ce1=0,ce2=0,ce3=0;
#pragma unroll
    for (int dy=0;dy<5;++dy) {
      const unsigned int* qrow = reinterpret_cast<const unsigned int*>(qrow0 + c*CTILE + dy*CROW);
      float2 t0 = h2f(qrow[0]);   // gx-2, gx-1
      float2 t1 = h2f(qrow[1]);   // gx  , gx+1
      float2 t2 = h2f(qrow[2]);   // gx+2, gx+3
      cs0+=t0.x; cs1+=t0.y; cs2+=t1.x; cs3+=t1.y; cs4+=t2.x; cs5+=t2.y;
      if (dy>=1 && dy<=3) {
        ce0 += t0.y*ew[dy-1][0];   // gx-1
        ce1 += t1.x*ew[dy-1][1];   // gx
        ce2 += t1.y*ew[dy-1][2];   // gx+1
        ce3 += t2.x*ew[dy-1][3];   // gx+2
      }
    }
    float v0 = cs0+cs1+cs2+cs3+cs4;      // 5-wide window @ gx
    float v1 = v0 - cs0 + cs5;           // @ gx+1
    float w0 = ce0+ce1+ce2;              // 3-wide window @ gx
    float w1 = ce1+ce2+ce3;              // @ gx+1
    msgr[c][0] = csw*v0 + cb0*w0;
    msgr[c][1] = csw*v1 + cb1*w1;
  }

  // ---- phase 2: (optional compat) + softmax over channels, in registers ----
  float mx0=-3e38f, mx1=-3e38f;

  if (fl) {   // identity compat fast path
#pragma unroll
    for (int c=0;c<NC;++c) {
      LOAD_U2(c, u0,u1)
      msgr[c][0] = u0 - msgr[c][0];
      msgr[c][1] = u1 - msgr[c][1];
      mx0=fmaxf(mx0,msgr[c][0]); mx1=fmaxf(mx1,msgr[c][1]);
    }
    float s0=0,s1=0;
#pragma unroll
    for (int c=0;c<NC;++c) {
      float e0=__expf(msgr[c][0]-mx0), e1=__expf(msgr[c][1]-mx1);
      msgr[c][0]=e0; msgr[c][1]=e1;
      s0+=e0; s1+=e1;
    }
    float r0=1.f/s0, r1=1.f/s1;
#pragma unroll
    for (int c=0;c<NC;++c) {
      float o0=msgr[c][0]*r0, o1=msgr[c][1]*r1;
      if (OUTF32) {
        reinterpret_cast<float2*>(Qout)[hbase + (size_t)c*ch] = make_float2(o0,o1);
      } else {
        reinterpret_cast<unsigned int*>(Qout)[hbase + (size_t)c*ch] = f2h(o0,o1);
      }
    }
  } else {    // general compat: recompute logits per pass (register-light)
#pragma unroll 1
    for (int c=0;c<NC;++c) {
      ACCUM_COMPAT2(c, a0,a1)
      LOAD_U2(c, u0,u1)
      mx0=fmaxf(mx0,u0-a0); mx1=fmaxf(mx1,u1-a1);
    }
    float s0=0,s1=0;
#pragma unroll 1
    for (int c=0;c<NC;++c) {
      ACCUM_COMPAT2(c, a0,a1)
      LOAD_U2(c, u0,u1)
      s0+=__expf(u0-a0-mx0); s1+=__expf(u1-a1-mx1);
    }
    float r0=1.f/s0, r1=1.f/s1;
#pragma unroll 1
    for (int c=0;c<NC;++c) {
      ACCUM_COMPAT2(c, a0,a1)
      LOAD_U2(c, u0,u1)
      float o0=__expf(u0-a0-mx0)*r0, o1=__expf(u1-a1-mx1)*r1;
      if (OUTF32) {
        reinterpret_cast<float2*>(Qout)[hbase + (size_t)c*ch] = make_float2(o0,o1);
      } else {
        reinterpret_cast<unsigned int*>(Qout)[hbase + (size_t)c*ch] = f2h(o0,o1);
      }
    }
  }
}

extern "C" void kernel_launch(void* const* d_in, const int* in_sizes, int n_in,
                              void* d_out, int out_size, void* d_ws, size_t ws_size,
                              hipStream_t stream)
{
  const float* unary  = (const float*)d_in[0];
  const float* image  = (const float*)d_in[1];
  const float* compat = (const float*)d_in[2];
  const float* swp    = (const float*)d_in[3];
  const float* bwp    = (const float*)d_in[4];

  // ws layout (bytes): X fp16 Q buffer | edge16 | rnorm | flag | (opt) u16
  char* ws = (char*)d_ws;
  __half* X      = (__half*)(ws + 0);            // 88,080,384 B
  __half* edge16 = (__half*)(ws + 88080384);     //  4,194,304 B
  float*  rnorm  = (float*) (ws + 92274688);     //  8,388,608 B
  int*    flag   = (int*)   (ws + 100663296);    //        256 B
  __half* u16    = (__half*)(ws + 100663552);    // 88,080,384 B (optional)
  if (ws_size < (size_t)100663552) return;       // cannot run without scratch
  const bool use_u16 = (ws_size >= (size_t)188743936);

  __half* Y  = (__half*)d_out;   // d_out doubles as fp16 scratch during iters
  float* out = (float*)d_out;

  k_edge   <<<dim3(8192), dim3(256), 0, stream>>>(image, edge16);
  k_rnorm  <<<dim3(8192), dim3(256), 0, stream>>>(edge16, rnorm);
  k_flag   <<<dim3(1),    dim3(256), 0, stream>>>(compat, flag);
  if (use_u16) k_cvt<<<dim3(43008), dim3(256), 0, stream>>>(unary, u16);
  k_softmax0<<<dim3(2048), dim3(256), 0, stream>>>(unary, Y);

  const void* up = use_u16 ? (const void*)u16 : (const void*)unary;
  dim3 gi(8, 64, NB), bi(256);
  // Q0 -> Y(d_out,fp16); odd iters Y->X; even iters X->Y; iter10 X -> d_out fp32
  for (int it = 1; it <= 10; ++it) {
    const __half* qin = (it & 1) ? Y : X;
    if (it == 10) {
      if (use_u16) k_iter<true , true ><<<gi,bi,0,stream>>>(qin,(void*)out,up,edge16,rnorm,swp,bwp,compat,flag);
      else         k_iter<false, true ><<<gi,bi,0,stream>>>(qin,(void*)out,up,edge16,rnorm,swp,bwp,compat,flag);
    } else {
      void* qout = (it & 1) ? (void*)X : (void*)Y;
      if (use_u16) k_iter<true , false><<<gi,bi,0,stream>>>(qin,qout,up,edge16,rnorm,swp,bwp,compat,flag);
      else         k_iter<false, false><<<gi,bi,0,stream>>>(qin,qout,up,edge16,rnorm,swp,bwp,compat,flag);
    }
  }
}

// Round 6
// 2997.313 us; speedup vs baseline: 1.9380x; 1.9380x over previous
//
#include <hip/hip_runtime.h>
#include <hip/hip_fp16.h>

#define PLANE 262144   // 512*512
#define NC 21
#define NB 8
#define NPIX (NB*PLANE)

__device__ __forceinline__ float2 h2f(unsigned int u) {
  union { unsigned int u; __half2 h; } x; x.u = u;
  return __half22float2(x.h);
}
__device__ __forceinline__ unsigned int f2h(float a, float b) {
  union { unsigned int u; __half2 h; } x;
  x.h = __floats2half2_rn(a, b);
  return x.u;
}

// ---------------- prep: edge = exp(-|sobel(gray)|) ----------------
__global__ __launch_bounds__(256)
void k_edge(const float* __restrict__ img, __half* __restrict__ edge16) {
  int id = blockIdx.x*256 + threadIdx.x;
  int b = id >> 18;
  int rem = id & (PLANE-1);
  int y = rem >> 9, x = rem & 511;
  const float* ib = img + (size_t)b*3*PLANE;
  float g[3][3];
#pragma unroll
  for (int dy=0; dy<3; ++dy)
#pragma unroll
    for (int dx=0; dx<3; ++dx) {
      int yy = y+dy-1, xx = x+dx-1;
      float v = 0.f;
      if (yy>=0 && yy<512 && xx>=0 && xx<512) {
        int o = (yy<<9)|xx;
        v = 0.299f*ib[o] + 0.587f*ib[o+PLANE] + 0.114f*ib[o+2*PLANE];
      }
      g[dy][dx]=v;
    }
  float gxv = (g[0][2]-g[0][0]) + 2.f*(g[1][2]-g[1][0]) + (g[2][2]-g[2][0]);
  float gyv = (g[2][0]-g[0][0]) + 2.f*(g[2][1]-g[0][1]) + (g[2][2]-g[0][2]);
  float mag = sqrtf(gxv*gxv + gyv*gyv + 1e-6f);
  edge16[id] = __float2half(__expf(-mag));
}

// ---------------- prep: rnorm = 1/(avgpool3(edge)+1e-6) ----------------
__global__ __launch_bounds__(256)
void k_rnorm(const __half* __restrict__ edge16, float* __restrict__ rnorm) {
  int id = blockIdx.x*256 + threadIdx.x;
  int b = id >> 18;
  int rem = id & (PLANE-1);
  int y = rem >> 9, x = rem & 511;
  const __half* eb = edge16 + (size_t)b*PLANE;
  float s = 0.f;
#pragma unroll
  for (int dy=-1; dy<=1; ++dy)
#pragma unroll
    for (int dx=-1; dx<=1; ++dx) {
      int yy = y+dy, xx = x+dx;
      if (yy>=0 && yy<512 && xx>=0 && xx<512) s += __half2float(eb[(yy<<9)|xx]);
    }
  rnorm[id] = 1.f/(s*(1.f/9.f) + 1e-6f);
}

// ---------------- prep: compat == identity? ----------------
__global__ void k_flag(const float* __restrict__ compat, int* __restrict__ flag) {
  __shared__ int ok;
  if (threadIdx.x==0) ok = 1;
  __syncthreads();
  int bad = 0;
  for (int i = threadIdx.x; i < NC*NC; i += 256) {
    float exp = ((i/NC) == (i%NC)) ? 1.f : 0.f;
    if (compat[i] != exp) bad = 1;
  }
  if (bad) atomicAnd(&ok, 0);
  __syncthreads();
  if (threadIdx.x==0) flag[0] = ok;
}

// ---------------- prep: unary fp32 -> fp16 ----------------
__global__ __launch_bounds__(256)
void k_cvt(const float* __restrict__ u, __half* __restrict__ u16) {
  size_t q = (size_t)blockIdx.x*256 + threadIdx.x;
  float4 v = reinterpret_cast<const float4*>(u)[q];
  uint2 w; w.x = f2h(v.x, v.y); w.y = f2h(v.z, v.w);
  reinterpret_cast<uint2*>(u16)[q] = w;
}

// ---------------- Q0 = softmax(unary) -> fp16 ----------------
__global__ __launch_bounds__(256)
void k_softmax0(const float* __restrict__ unary, __half* __restrict__ Y) {
  int q = blockIdx.x*256 + threadIdx.x;           // quad id, [0, NPIX/4)
  int b = q >> 16;
  int rem = q & 65535;
  size_t base = (size_t)b*NC*(PLANE>>2) + rem;
  const float4* up = reinterpret_cast<const float4*>(unary);
  float v[NC][4];
  float mx0=-3e38f,mx1=-3e38f,mx2=-3e38f,mx3=-3e38f;
#pragma unroll
  for (int c=0;c<NC;++c) {
    float4 t = up[base + (size_t)c*(PLANE>>2)];
    v[c][0]=t.x; v[c][1]=t.y; v[c][2]=t.z; v[c][3]=t.w;
    mx0=fmaxf(mx0,t.x); mx1=fmaxf(mx1,t.y); mx2=fmaxf(mx2,t.z); mx3=fmaxf(mx3,t.w);
  }
  float s0=0,s1=0,s2=0,s3=0;
#pragma unroll
  for (int c=0;c<NC;++c) {
    float e0=__expf(v[c][0]-mx0), e1=__expf(v[c][1]-mx1);
    float e2=__expf(v[c][2]-mx2), e3=__expf(v[c][3]-mx3);
    v[c][0]=e0; v[c][1]=e1; v[c][2]=e2; v[c][3]=e3;
    s0+=e0; s1+=e1; s2+=e2; s3+=e3;
  }
  float r0=1.f/s0, r1=1.f/s1, r2=1.f/s2, r3=1.f/s3;
  uint2* yp = reinterpret_cast<uint2*>(Y);
#pragma unroll
  for (int c=0;c<NC;++c) {
    uint2 w; w.x=f2h(v[c][0]*r0, v[c][1]*r1); w.y=f2h(v[c][2]*r2, v[c][3]*r3);
    yp[base + (size_t)c*(PLANE>>2)] = w;
  }
}

// ---------------- fused CRF iteration ----------------
// R6: channel-pipelined ping-pong staging (T3 "minimum 2-phase" pattern).
// R5 post-mortem: upf prefetch + min-waves bound -> VGPR 64, 1.1 GB/iter
// spills. NEVER min-waves-hint this kernel; never hold long-lived prefetch
// arrays. R4 re-read: WRITE 344-434 MB vs 84 real -> R4 STILL spilled
// ~250 MB/iter (spill reloads hit L2, stores evict to HBM); and burst-stage->
// barrier->compute leaves HBM idle during compute (VALU 24%, HBM 30%).
// Now: stage ONE channel tile/iteration into a 2-buffer LDS ping-pong
// (LDS 8.6 KB), fully-unrolled channel loop (msgr static-indexed, rule #20),
// barrier per channel. Load for c+1 issued before compute c -> latency
// hidden; only one channel's regs/ds_reads can be hoisted -> live set ~92,
// no spills. 2 px/thread, 512 threads, tile 64x16.

#define LOAD_U2(c, u0,u1) \
  float u0,u1; \
  if (U16) { unsigned int w_ = reinterpret_cast<const unsigned int*>(uptr)[hbase + (size_t)(c)*ch]; \
    float2 t_=h2f(w_); u0=t_.x; u1=t_.y; } \
  else { float2 v_ = reinterpret_cast<const float2*>(uptr)[hbase + (size_t)(c)*ch]; \
    u0=v_.x; u1=v_.y; }

#define ACCUM_COMPAT2(c, a0,a1) \
  float a0=0.f,a1=0.f; \
  _Pragma("unroll") \
  for (int d=0; d<NC; ++d) { float cf_ = compat[(c)*NC+d]; \
    a0 += cf_*msgr[d][0]; a1 += cf_*msgr[d][1]; }

#define CROW 72            // LDS row stride (halves) == staged cols
#define TROWS 20           // staged rows (16 tile + 4 halo)
#define CTILE (TROWS*CROW) // halves per channel buffer (1440)

template<bool U16, bool OUTF32>
__global__ __launch_bounds__(512)
void k_iter(const __half* __restrict__ Qin,
            void* __restrict__ Qout,
            const void* __restrict__ uptr,
            const __half* __restrict__ edge16,
            const float* __restrict__ rnorm,
            const float* __restrict__ swp,
            const float* __restrict__ bwp,
            const float* __restrict__ compat,
            const int* __restrict__ flag)
{
  __shared__ __half qbuf[2][CTILE];   // 2 x 20 x 72 halves = 5760 B
  __shared__ __half et[CTILE];        //     20 x 72 halves = 2880 B

  const int tid = threadIdx.x;
  const int tx = tid & 31;        // 32 threads across 64 px, 2 px each
  const int ty = tid >> 5;        // 16 rows
  const int x0 = blockIdx.x << 6;
  const int y0 = blockIdx.y << 4;
  const int b  = blockIdx.z;

  // ---- staging slot: 20 rows x 18 uint2 (4 halves) = 360 slots ----
  const int slot = tid;
  const int sr = slot / 18;
  const int si = slot - sr*18;
  const int sy = y0 - 2 + sr;                 // rows y0-2 .. y0+17
  const int sx = x0 - 4 + (si<<2);            // cols x0-4 .. x0+67, step 4
  const bool sact = (slot < 360);
  const bool sval = sact && (sy>=0) && (sy<512) && (sx>=0) && (sx<512);
  const int  goff = (sy<<9) + sx;             // halves into plane (use iff sval)
  const int  loff = sr*CROW + (si<<2);        // halves into tile

  const int gy  = y0 + ty;
  const int gx  = x0 + (tx<<1);
  const int pix = (gy<<9) | gx;

  // early independent loads (overlap with staging latency)
  const float2 rn = *reinterpret_cast<const float2*>(rnorm + (size_t)b*PLANE + pix);
  const float sw  = fmaxf(swp[0], 0.f);
  const float bw  = fmaxf(bwp[0], 0.f);
  const int fl = flag[0];

  // ---- prologue: stage edge tile + channel 0 tile, one barrier ----
  const __half* qb = Qin + (size_t)b*NC*PLANE;
  {
    const __half* ep = edge16 + (size_t)b*PLANE;
    uint2 we = make_uint2(0u, 0u);
    uint2 w0 = make_uint2(0u, 0u);
    if (sval) {
      we = *reinterpret_cast<const uint2*>(ep + goff);
      w0 = *reinterpret_cast<const uint2*>(qb + goff);
    }
    if (sact) {
      *reinterpret_cast<uint2*>(et + loff) = we;
      *reinterpret_cast<uint2*>(qbuf[0] + loff) = w0;
    }
  }
  __syncthreads();

  const float csw = sw * 0.04f;          // sw/25
  const float b9  = bw * (1.f/9.f);      // bw/9
  const float cb0 = b9*rn.x, cb1 = b9*rn.y;

  const int lx2 = (tx<<1) + 2;           // LDS col of gx-2 (staged region shift)

  // hoist edge window into registers once (channel-invariant):
  // rows ty+1..ty+3, global cols gx-1..gx+2 = staged cols lx2+1..lx2+4
  float ew[3][4];
#pragma unroll
  for (int dy=0;dy<3;++dy) {
    const unsigned int* erow = reinterpret_cast<const unsigned int*>(et + (ty+1+dy)*CROW + lx2);
    float2 e0 = h2f(erow[0]);
    float2 e1 = h2f(erow[1]);
    float2 e2 = h2f(erow[2]);
    ew[dy][0]=e0.y; ew[dy][1]=e1.x; ew[dy][2]=e1.y; ew[dy][3]=e2.x;
  }

  // ---- pipelined channel loop: load c+1 | compute c | write c+1 | barrier ----
  float msgr[NC][2];

#pragma unroll
  for (int c=0;c<NC;++c) {
    // issue next channel's staging load early (hidden under compute)
    uint2 wn = make_uint2(0u, 0u);
    if (c+1 < NC && sval)
      wn = *reinterpret_cast<const uint2*>(qb + (size_t)(c+1)*PLANE + goff);

    // compute msgr[c] from qbuf[c&1] (pure LDS)
    const __half* qrow0 = qbuf[c&1] + ty*CROW + lx2;
    float cs0=0,cs1=0,cs2=0,cs3=0,cs4=0,cs5=0;
    float ce0=0,ce1=0,ce2=0,ce3=0;
#pragma unroll
    for (int dy=0;dy<5;++dy) {
      const unsigned int* qrow = reinterpret_cast<const unsigned int*>(qrow0 + dy*CROW);
      float2 t0 = h2f(qrow[0]);   // gx-2, gx-1
      float2 t1 = h2f(qrow[1]);   // gx  , gx+1
      float2 t2 = h2f(qrow[2]);   // gx+2, gx+3
      cs0+=t0.x; cs1+=t0.y; cs2+=t1.x; cs3+=t1.y; cs4+=t2.x; cs5+=t2.y;
      if (dy>=1 && dy<=3) {
        ce0 += t0.y*ew[dy-1][0];   // gx-1
        ce1 += t1.x*ew[dy-1][1];   // gx
        ce2 += t1.y*ew[dy-1][2];   // gx+1
        ce3 += t2.x*ew[dy-1][3];   // gx+2
      }
    }
    float v0 = cs0+cs1+cs2+cs3+cs4;      // 5-wide window @ gx
    float v1 = v0 - cs0 + cs5;           // @ gx+1
    float w0 = ce0+ce1+ce2;              // 3-wide window @ gx
    float w1 = ce1+ce2+ce3;              // @ gx+1
    msgr[c][0] = csw*v0 + cb0*w0;
    msgr[c][1] = csw*v1 + cb1*w1;

    // commit next channel's tile to the other buffer, then sync
    if (c+1 < NC) {
      if (sact) *reinterpret_cast<uint2*>(qbuf[(c+1)&1] + loff) = wn;
      __syncthreads();
    }
  }

  // ---- phase 2: (optional compat) + softmax over channels, in registers ----
  const size_t hbase = (((size_t)b*NC*PLANE) + (size_t)pix) >> 1;  // half2 / float2 units
  const size_t ch = PLANE >> 1;
  float mx0=-3e38f, mx1=-3e38f;

  if (fl) {   // identity compat fast path
#pragma unroll
    for (int c=0;c<NC;++c) {
      LOAD_U2(c, u0,u1)
      msgr[c][0] = u0 - msgr[c][0];
      msgr[c][1] = u1 - msgr[c][1];
      mx0=fmaxf(mx0,msgr[c][0]); mx1=fmaxf(mx1,msgr[c][1]);
    }
    float s0=0,s1=0;
#pragma unroll
    for (int c=0;c<NC;++c) {
      float e0=__expf(msgr[c][0]-mx0), e1=__expf(msgr[c][1]-mx1);
      msgr[c][0]=e0; msgr[c][1]=e1;
      s0+=e0; s1+=e1;
    }
    float r0=1.f/s0, r1=1.f/s1;
#pragma unroll
    for (int c=0;c<NC;++c) {
      float o0=msgr[c][0]*r0, o1=msgr[c][1]*r1;
      if (OUTF32) {
        reinterpret_cast<float2*>(Qout)[hbase + (size_t)c*ch] = make_float2(o0,o1);
      } else {
        reinterpret_cast<unsigned int*>(Qout)[hbase + (size_t)c*ch] = f2h(o0,o1);
      }
    }
  } else {    // general compat: recompute logits per pass (register-light)
#pragma unroll 1
    for (int c=0;c<NC;++c) {
      ACCUM_COMPAT2(c, a0,a1)
      LOAD_U2(c, u0,u1)
      mx0=fmaxf(mx0,u0-a0); mx1=fmaxf(mx1,u1-a1);
    }
    float s0=0,s1=0;
#pragma unroll 1
    for (int c=0;c<NC;++c) {
      ACCUM_COMPAT2(c, a0,a1)
      LOAD_U2(c, u0,u1)
      s0+=__expf(u0-a0-mx0); s1+=__expf(u1-a1-mx1);
    }
    float r0=1.f/s0, r1=1.f/s1;
#pragma unroll 1
    for (int c=0;c<NC;++c) {
      ACCUM_COMPAT2(c, a0,a1)
      LOAD_U2(c, u0,u1)
      float o0=__expf(u0-a0-mx0)*r0, o1=__expf(u1-a1-mx1)*r1;
      if (OUTF32) {
        reinterpret_cast<float2*>(Qout)[hbase + (size_t)c*ch] = make_float2(o0,o1);
      } else {
        reinterpret_cast<unsigned int*>(Qout)[hbase + (size_t)c*ch] = f2h(o0,o1);
      }
    }
  }
}

extern "C" void kernel_launch(void* const* d_in, const int* in_sizes, int n_in,
                              void* d_out, int out_size, void* d_ws, size_t ws_size,
                              hipStream_t stream)
{
  const float* unary  = (const float*)d_in[0];
  const float* image  = (const float*)d_in[1];
  const float* compat = (const float*)d_in[2];
  const float* swp    = (const float*)d_in[3];
  const float* bwp    = (const float*)d_in[4];

  // ws layout (bytes): X fp16 Q buffer | edge16 | rnorm | flag | (opt) u16
  char* ws = (char*)d_ws;
  __half* X      = (__half*)(ws + 0);            // 88,080,384 B
  __half* edge16 = (__half*)(ws + 88080384);     //  4,194,304 B
  float*  rnorm  = (float*) (ws + 92274688);     //  8,388,608 B
  int*    flag   = (int*)   (ws + 100663296);    //        256 B
  __half* u16    = (__half*)(ws + 100663552);    // 88,080,384 B (optional)
  if (ws_size < (size_t)100663552) return;       // cannot run without scratch
  const bool use_u16 = (ws_size >= (size_t)188743936);

  __half* Y  = (__half*)d_out;   // d_out doubles as fp16 scratch during iters
  float* out = (float*)d_out;

  k_edge   <<<dim3(8192), dim3(256), 0, stream>>>(image, edge16);
  k_rnorm  <<<dim3(8192), dim3(256), 0, stream>>>(edge16, rnorm);
  k_flag   <<<dim3(1),    dim3(256), 0, stream>>>(compat, flag);
  if (use_u16) k_cvt<<<dim3(43008), dim3(256), 0, stream>>>(unary, u16);
  k_softmax0<<<dim3(2048), dim3(256), 0, stream>>>(unary, Y);

  const void* up = use_u16 ? (const void*)u16 : (const void*)unary;
  dim3 gi(8, 32, NB), bi(512);
  // Q0 -> Y(d_out,fp16); odd iters Y->X; even iters X->Y; iter10 X -> d_out fp32
  for (int it = 1; it <= 10; ++it) {
    const __half* qin = (it & 1) ? Y : X;
    if (it == 10) {
      if (use_u16) k_iter<true , true ><<<gi,bi,0,stream>>>(qin,(void*)out,up,edge16,rnorm,swp,bwp,compat,flag);
      else         k_iter<false, true ><<<gi,bi,0,stream>>>(qin,(void*)out,up,edge16,rnorm,swp,bwp,compat,flag);
    } else {
      void* qout = (it & 1) ? (void*)X : (void*)Y;
      if (use_u16) k_iter<true , false><<<gi,bi,0,stream>>>(qin,qout,up,edge16,rnorm,swp,bwp,compat,flag);
      else         k_iter<false, false><<<gi,bi,0,stream>>>(qin,qout,up,edge16,rnorm,swp,bwp,compat,flag);
    }
  }
}

// Round 7
// 2991.844 us; speedup vs baseline: 1.9415x; 1.0018x over previous
//
#include <hip/hip_runtime.h>
#include <hip/hip_fp16.h>

#define PLANE 262144   // 512*512
#define NC 21
#define NB 8
#define NPIX (NB*PLANE)

__device__ __forceinline__ float2 h2f(unsigned int u) {
  union { unsigned int u; __half2 h; } x; x.u = u;
  return __half22float2(x.h);
}
__device__ __forceinline__ unsigned int f2h(float a, float b) {
  union { unsigned int u; __half2 h; } x;
  x.h = __floats2half2_rn(a, b);
  return x.u;
}

// ---------------- prep: edge = exp(-|sobel(gray)|) ----------------
__global__ __launch_bounds__(256)
void k_edge(const float* __restrict__ img, __half* __restrict__ edge16) {
  int id = blockIdx.x*256 + threadIdx.x;
  int b = id >> 18;
  int rem = id & (PLANE-1);
  int y = rem >> 9, x = rem & 511;
  const float* ib = img + (size_t)b*3*PLANE;
  float g[3][3];
#pragma unroll
  for (int dy=0; dy<3; ++dy)
#pragma unroll
    for (int dx=0; dx<3; ++dx) {
      int yy = y+dy-1, xx = x+dx-1;
      float v = 0.f;
      if (yy>=0 && yy<512 && xx>=0 && xx<512) {
        int o = (yy<<9)|xx;
        v = 0.299f*ib[o] + 0.587f*ib[o+PLANE] + 0.114f*ib[o+2*PLANE];
      }
      g[dy][dx]=v;
    }
  float gxv = (g[0][2]-g[0][0]) + 2.f*(g[1][2]-g[1][0]) + (g[2][2]-g[2][0]);
  float gyv = (g[2][0]-g[0][0]) + 2.f*(g[2][1]-g[0][1]) + (g[2][2]-g[0][2]);
  float mag = sqrtf(gxv*gxv + gyv*gyv + 1e-6f);
  edge16[id] = __float2half(__expf(-mag));
}

// ---------------- prep: rnorm = 1/(avgpool3(edge)+1e-6) ----------------
__global__ __launch_bounds__(256)
void k_rnorm(const __half* __restrict__ edge16, float* __restrict__ rnorm) {
  int id = blockIdx.x*256 + threadIdx.x;
  int b = id >> 18;
  int rem = id & (PLANE-1);
  int y = rem >> 9, x = rem & 511;
  const __half* eb = edge16 + (size_t)b*PLANE;
  float s = 0.f;
#pragma unroll
  for (int dy=-1; dy<=1; ++dy)
#pragma unroll
    for (int dx=-1; dx<=1; ++dx) {
      int yy = y+dy, xx = x+dx;
      if (yy>=0 && yy<512 && xx>=0 && xx<512) s += __half2float(eb[(yy<<9)|xx]);
    }
  rnorm[id] = 1.f/(s*(1.f/9.f) + 1e-6f);
}

// ---------------- prep: compat == identity? ----------------
__global__ void k_flag(const float* __restrict__ compat, int* __restrict__ flag) {
  __shared__ int ok;
  if (threadIdx.x==0) ok = 1;
  __syncthreads();
  int bad = 0;
  for (int i = threadIdx.x; i < NC*NC; i += 256) {
    float exp = ((i/NC) == (i%NC)) ? 1.f : 0.f;
    if (compat[i] != exp) bad = 1;
  }
  if (bad) atomicAnd(&ok, 0);
  __syncthreads();
  if (threadIdx.x==0) flag[0] = ok;
}

// ---------------- prep: unary fp32 -> fp16 ----------------
__global__ __launch_bounds__(256)
void k_cvt(const float* __restrict__ u, __half* __restrict__ u16) {
  size_t q = (size_t)blockIdx.x*256 + threadIdx.x;
  float4 v = reinterpret_cast<const float4*>(u)[q];
  uint2 w; w.x = f2h(v.x, v.y); w.y = f2h(v.z, v.w);
  reinterpret_cast<uint2*>(u16)[q] = w;
}

// ---------------- Q0 = softmax(unary) -> fp16 ----------------
__global__ __launch_bounds__(256)
void k_softmax0(const float* __restrict__ unary, __half* __restrict__ Y) {
  int q = blockIdx.x*256 + threadIdx.x;           // quad id, [0, NPIX/4)
  int b = q >> 16;
  int rem = q & 65535;
  size_t base = (size_t)b*NC*(PLANE>>2) + rem;
  const float4* up = reinterpret_cast<const float4*>(unary);
  float v[NC][4];
  float mx0=-3e38f,mx1=-3e38f,mx2=-3e38f,mx3=-3e38f;
#pragma unroll
  for (int c=0;c<NC;++c) {
    float4 t = up[base + (size_t)c*(PLANE>>2)];
    v[c][0]=t.x; v[c][1]=t.y; v[c][2]=t.z; v[c][3]=t.w;
    mx0=fmaxf(mx0,t.x); mx1=fmaxf(mx1,t.y); mx2=fmaxf(mx2,t.z); mx3=fmaxf(mx3,t.w);
  }
  float s0=0,s1=0,s2=0,s3=0;
#pragma unroll
  for (int c=0;c<NC;++c) {
    float e0=__expf(v[c][0]-mx0), e1=__expf(v[c][1]-mx1);
    float e2=__expf(v[c][2]-mx2), e3=__expf(v[c][3]-mx3);
    v[c][0]=e0; v[c][1]=e1; v[c][2]=e2; v[c][3]=e3;
    s0+=e0; s1+=e1; s2+=e2; s3+=e3;
  }
  float r0=1.f/s0, r1=1.f/s1, r2=1.f/s2, r3=1.f/s3;
  uint2* yp = reinterpret_cast<uint2*>(Y);
#pragma unroll
  for (int c=0;c<NC;++c) {
    uint2 w; w.x=f2h(v[c][0]*r0, v[c][1]*r1); w.y=f2h(v[c][2]*r2, v[c][3]*r3);
    yp[base + (size_t)c*(PLANE>>2)] = w;
  }
}

// ---------------- fused CRF iteration ----------------
// R7 = R6 + sched_barrier(0) fences. R6 post-mortem: WRITE_SIZE decomposes as
// integer multiples of the Q footprint (R3 4.00x, R6 5.14x) -> msgr[21][2]
// (168 B/thread = 2xQ per write pass) lives in SCRATCH. Root cause: global
// loads cross s_barrier at schedule time; the fully-unrolled channel loop's
// prefetch loads all hoist to the top, inflating live set past the 128 cap,
// and the allocator sacrifices the long-lived msgr to scratch. Fix: one
// __builtin_amdgcn_sched_barrier(0) after each __syncthreads() pins each
// channel's load to its own iteration (max 1 prefetch in flight). KEY
// PREDICTION: WRITE_SIZE 442368 -> ~1.0-1.2x Q (~90-110k KiB).

#define LOAD_U2(c, u0,u1) \
  float u0,u1; \
  if (U16) { unsigned int w_ = reinterpret_cast<const unsigned int*>(uptr)[hbase + (size_t)(c)*ch]; \
    float2 t_=h2f(w_); u0=t_.x; u1=t_.y; } \
  else { float2 v_ = reinterpret_cast<const float2*>(uptr)[hbase + (size_t)(c)*ch]; \
    u0=v_.x; u1=v_.y; }

#define ACCUM_COMPAT2(c, a0,a1) \
  float a0=0.f,a1=0.f; \
  _Pragma("unroll") \
  for (int d=0; d<NC; ++d) { float cf_ = compat[(c)*NC+d]; \
    a0 += cf_*msgr[d][0]; a1 += cf_*msgr[d][1]; }

#define CROW 72            // LDS row stride (halves) == staged cols
#define TROWS 20           // staged rows (16 tile + 4 halo)
#define CTILE (TROWS*CROW) // halves per channel buffer (1440)

template<bool U16, bool OUTF32>
__global__ __launch_bounds__(512)
void k_iter(const __half* __restrict__ Qin,
            void* __restrict__ Qout,
            const void* __restrict__ uptr,
            const __half* __restrict__ edge16,
            const float* __restrict__ rnorm,
            const float* __restrict__ swp,
            const float* __restrict__ bwp,
            const float* __restrict__ compat,
            const int* __restrict__ flag)
{
  __shared__ __half qbuf[2][CTILE];   // 2 x 20 x 72 halves = 5760 B
  __shared__ __half et[CTILE];        //     20 x 72 halves = 2880 B

  const int tid = threadIdx.x;
  const int tx = tid & 31;        // 32 threads across 64 px, 2 px each
  const int ty = tid >> 5;        // 16 rows
  const int x0 = blockIdx.x << 6;
  const int y0 = blockIdx.y << 4;
  const int b  = blockIdx.z;

  // ---- staging slot: 20 rows x 18 uint2 (4 halves) = 360 slots ----
  const int slot = tid;
  const int sr = slot / 18;
  const int si = slot - sr*18;
  const int sy = y0 - 2 + sr;                 // rows y0-2 .. y0+17
  const int sx = x0 - 4 + (si<<2);            // cols x0-4 .. x0+67, step 4
  const bool sact = (slot < 360);
  const bool sval = sact && (sy>=0) && (sy<512) && (sx>=0) && (sx<512);
  const int  goff = (sy<<9) + sx;             // halves into plane (use iff sval)
  const int  loff = sr*CROW + (si<<2);        // halves into tile

  const int gy  = y0 + ty;
  const int gx  = x0 + (tx<<1);
  const int pix = (gy<<9) | gx;

  // early independent loads (overlap with staging latency)
  const float2 rn = *reinterpret_cast<const float2*>(rnorm + (size_t)b*PLANE + pix);
  const float sw  = fmaxf(swp[0], 0.f);
  const float bw  = fmaxf(bwp[0], 0.f);
  const int fl = flag[0];

  // ---- prologue: stage edge tile + channel 0 tile, one barrier ----
  const __half* qb = Qin + (size_t)b*NC*PLANE;
  {
    const __half* ep = edge16 + (size_t)b*PLANE;
    uint2 we = make_uint2(0u, 0u);
    uint2 w0 = make_uint2(0u, 0u);
    if (sval) {
      we = *reinterpret_cast<const uint2*>(ep + goff);
      w0 = *reinterpret_cast<const uint2*>(qb + goff);
    }
    if (sact) {
      *reinterpret_cast<uint2*>(et + loff) = we;
      *reinterpret_cast<uint2*>(qbuf[0] + loff) = w0;
    }
  }
  __syncthreads();
  __builtin_amdgcn_sched_barrier(0);   // fence: nothing crosses the prologue

  const float csw = sw * 0.04f;          // sw/25
  const float b9  = bw * (1.f/9.f);      // bw/9
  const float cb0 = b9*rn.x, cb1 = b9*rn.y;

  const int lx2 = (tx<<1) + 2;           // LDS col of gx-2 (staged region shift)

  // hoist edge window into registers once (channel-invariant):
  // rows ty+1..ty+3, global cols gx-1..gx+2 = staged cols lx2+1..lx2+4
  float ew[3][4];
#pragma unroll
  for (int dy=0;dy<3;++dy) {
    const unsigned int* erow = reinterpret_cast<const unsigned int*>(et + (ty+1+dy)*CROW + lx2);
    float2 e0 = h2f(erow[0]);
    float2 e1 = h2f(erow[1]);
    float2 e2 = h2f(erow[2]);
    ew[dy][0]=e0.y; ew[dy][1]=e1.x; ew[dy][2]=e1.y; ew[dy][3]=e2.x;
  }

  // ---- pipelined channel loop: load c+1 | compute c | write c+1 | barrier ----
  float msgr[NC][2];

#pragma unroll
  for (int c=0;c<NC;++c) {
    // issue next channel's staging load early (hidden under compute)
    uint2 wn = make_uint2(0u, 0u);
    if (c+1 < NC && sval)
      wn = *reinterpret_cast<const uint2*>(qb + (size_t)(c+1)*PLANE + goff);

    // compute msgr[c] from qbuf[c&1] (pure LDS)
    const __half* qrow0 = qbuf[c&1] + ty*CROW + lx2;
    float cs0=0,cs1=0,cs2=0,cs3=0,cs4=0,cs5=0;
    float ce0=0,ce1=0,ce2=0,ce3=0;
#pragma unroll
    for (int dy=0;dy<5;++dy) {
      const unsigned int* qrow = reinterpret_cast<const unsigned int*>(qrow0 + dy*CROW);
      float2 t0 = h2f(qrow[0]);   // gx-2, gx-1
      float2 t1 = h2f(qrow[1]);   // gx  , gx+1
      float2 t2 = h2f(qrow[2]);   // gx+2, gx+3
      cs0+=t0.x; cs1+=t0.y; cs2+=t1.x; cs3+=t1.y; cs4+=t2.x; cs5+=t2.y;
      if (dy>=1 && dy<=3) {
        ce0 += t0.y*ew[dy-1][0];   // gx-1
        ce1 += t1.x*ew[dy-1][1];   // gx
        ce2 += t1.y*ew[dy-1][2];   // gx+1
        ce3 += t2.x*ew[dy-1][3];   // gx+2
      }
    }
    float v0 = cs0+cs1+cs2+cs3+cs4;      // 5-wide window @ gx
    float v1 = v0 - cs0 + cs5;           // @ gx+1
    float w0 = ce0+ce1+ce2;              // 3-wide window @ gx
    float w1 = ce1+ce2+ce3;              // @ gx+1
    msgr[c][0] = csw*v0 + cb0*w0;
    msgr[c][1] = csw*v1 + cb1*w1;

    // commit next channel's tile to the other buffer, then sync
    if (c+1 < NC) {
      if (sact) *reinterpret_cast<uint2*>(qbuf[(c+1)&1] + loff) = wn;
      __syncthreads();
      __builtin_amdgcn_sched_barrier(0);  // pin iteration c+1 below this point
    }
  }
  __builtin_amdgcn_sched_barrier(0);      // fence channel loop from phase 2

  // ---- phase 2: (optional compat) + softmax over channels, in registers ----
  const size_t hbase = (((size_t)b*NC*PLANE) + (size_t)pix) >> 1;  // half2 / float2 units
  const size_t ch = PLANE >> 1;
  float mx0=-3e38f, mx1=-3e38f;

  if (fl) {   // identity compat fast path
#pragma unroll
    for (int c=0;c<NC;++c) {
      LOAD_U2(c, u0,u1)
      msgr[c][0] = u0 - msgr[c][0];
      msgr[c][1] = u1 - msgr[c][1];
      mx0=fmaxf(mx0,msgr[c][0]); mx1=fmaxf(mx1,msgr[c][1]);
    }
    float s0=0,s1=0;
#pragma unroll
    for (int c=0;c<NC;++c) {
      float e0=__expf(msgr[c][0]-mx0), e1=__expf(msgr[c][1]-mx1);
      msgr[c][0]=e0; msgr[c][1]=e1;
      s0+=e0; s1+=e1;
    }
    float r0=1.f/s0, r1=1.f/s1;
#pragma unroll
    for (int c=0;c<NC;++c) {
      float o0=msgr[c][0]*r0, o1=msgr[c][1]*r1;
      if (OUTF32) {
        reinterpret_cast<float2*>(Qout)[hbase + (size_t)c*ch] = make_float2(o0,o1);
      } else {
        reinterpret_cast<unsigned int*>(Qout)[hbase + (size_t)c*ch] = f2h(o0,o1);
      }
    }
  } else {    // general compat: recompute logits per pass (register-light)
#pragma unroll 1
    for (int c=0;c<NC;++c) {
      ACCUM_COMPAT2(c, a0,a1)
      LOAD_U2(c, u0,u1)
      mx0=fmaxf(mx0,u0-a0); mx1=fmaxf(mx1,u1-a1);
    }
    float s0=0,s1=0;
#pragma unroll 1
    for (int c=0;c<NC;++c) {
      ACCUM_COMPAT2(c, a0,a1)
      LOAD_U2(c, u0,u1)
      s0+=__expf(u0-a0-mx0); s1+=__expf(u1-a1-mx1);
    }
    float r0=1.f/s0, r1=1.f/s1;
#pragma unroll 1
    for (int c=0;c<NC;++c) {
      ACCUM_COMPAT2(c, a0,a1)
      LOAD_U2(c, u0,u1)
      float o0=__expf(u0-a0-mx0)*r0, o1=__expf(u1-a1-mx1)*r1;
      if (OUTF32) {
        reinterpret_cast<float2*>(Qout)[hbase + (size_t)c*ch] = make_float2(o0,o1);
      } else {
        reinterpret_cast<unsigned int*>(Qout)[hbase + (size_t)c*ch] = f2h(o0,o1);
      }
    }
  }
}

extern "C" void kernel_launch(void* const* d_in, const int* in_sizes, int n_in,
                              void* d_out, int out_size, void* d_ws, size_t ws_size,
                              hipStream_t stream)
{
  const float* unary  = (const float*)d_in[0];
  const float* image  = (const float*)d_in[1];
  const float* compat = (const float*)d_in[2];
  const float* swp    = (const float*)d_in[3];
  const float* bwp    = (const float*)d_in[4];

  // ws layout (bytes): X fp16 Q buffer | edge16 | rnorm | flag | (opt) u16
  char* ws = (char*)d_ws;
  __half* X      = (__half*)(ws + 0);            // 88,080,384 B
  __half* edge16 = (__half*)(ws + 88080384);     //  4,194,304 B
  float*  rnorm  = (float*) (ws + 92274688);     //  8,388,608 B
  int*    flag   = (int*)   (ws + 100663296);    //        256 B
  __half* u16    = (__half*)(ws + 100663552);    // 88,080,384 B (optional)
  if (ws_size < (size_t)100663552) return;       // cannot run without scratch
  const bool use_u16 = (ws_size >= (size_t)188743936);

  __half* Y  = (__half*)d_out;   // d_out doubles as fp16 scratch during iters
  float* out = (float*)d_out;

  k_edge   <<<dim3(8192), dim3(256), 0, stream>>>(image, edge16);
  k_rnorm  <<<dim3(8192), dim3(256), 0, stream>>>(edge16, rnorm);
  k_flag   <<<dim3(1),    dim3(256), 0, stream>>>(compat, flag);
  if (use_u16) k_cvt<<<dim3(43008), dim3(256), 0, stream>>>(unary, u16);
  k_softmax0<<<dim3(2048), dim3(256), 0, stream>>>(unary, Y);

  const void* up = use_u16 ? (const void*)u16 : (const void*)unary;
  dim3 gi(8, 32, NB), bi(512);
  // Q0 -> Y(d_out,fp16); odd iters Y->X; even iters X->Y; iter10 X -> d_out fp32
  for (int it = 1; it <= 10; ++it) {
    const __half* qin = (it & 1) ? Y : X;
    if (it == 10) {
      if (use_u16) k_iter<true , true ><<<gi,bi,0,stream>>>(qin,(void*)out,up,edge16,rnorm,swp,bwp,compat,flag);
      else         k_iter<false, true ><<<gi,bi,0,stream>>>(qin,(void*)out,up,edge16,rnorm,swp,bwp,compat,flag);
    } else {
      void* qout = (it & 1) ? (void*)X : (void*)Y;
      if (use_u16) k_iter<true , false><<<gi,bi,0,stream>>>(qin,qout,up,edge16,rnorm,swp,bwp,compat,flag);
      else         k_iter<false, false><<<gi,bi,0,stream>>>(qin,qout,up,edge16,rnorm,swp,bwp,compat,flag);
    }
  }
}

// Round 8
// 1311.320 us; speedup vs baseline: 4.4296x; 2.2816x over previous
//
#include <hip/hip_runtime.h>
#include <hip/hip_fp16.h>

#define PLANE 262144   // 512*512
#define NC 21
#define NB 8
#define NPIX (NB*PLANE)

__device__ __forceinline__ float2 h2f(unsigned int u) {
  union { unsigned int u; __half2 h; } x; x.u = u;
  return __half22float2(x.h);
}
__device__ __forceinline__ unsigned int f2h(float a, float b) {
  union { unsigned int u; __half2 h; } x;
  x.h = __floats2half2_rn(a, b);
  return x.u;
}

// ---------------- prep: edge = exp(-|sobel(gray)|) ----------------
__global__ __launch_bounds__(256)
void k_edge(const float* __restrict__ img, __half* __restrict__ edge16) {
  int id = blockIdx.x*256 + threadIdx.x;
  int b = id >> 18;
  int rem = id & (PLANE-1);
  int y = rem >> 9, x = rem & 511;
  const float* ib = img + (size_t)b*3*PLANE;
  float g[3][3];
#pragma unroll
  for (int dy=0; dy<3; ++dy)
#pragma unroll
    for (int dx=0; dx<3; ++dx) {
      int yy = y+dy-1, xx = x+dx-1;
      float v = 0.f;
      if (yy>=0 && yy<512 && xx>=0 && xx<512) {
        int o = (yy<<9)|xx;
        v = 0.299f*ib[o] + 0.587f*ib[o+PLANE] + 0.114f*ib[o+2*PLANE];
      }
      g[dy][dx]=v;
    }
  float gxv = (g[0][2]-g[0][0]) + 2.f*(g[1][2]-g[1][0]) + (g[2][2]-g[2][0]);
  float gyv = (g[2][0]-g[0][0]) + 2.f*(g[2][1]-g[0][1]) + (g[2][2]-g[0][2]);
  float mag = sqrtf(gxv*gxv + gyv*gyv + 1e-6f);
  edge16[id] = __float2half(__expf(-mag));
}

// ---------------- prep: rnorm = 1/(avgpool3(edge)+1e-6) ----------------
__global__ __launch_bounds__(256)
void k_rnorm(const __half* __restrict__ edge16, float* __restrict__ rnorm) {
  int id = blockIdx.x*256 + threadIdx.x;
  int b = id >> 18;
  int rem = id & (PLANE-1);
  int y = rem >> 9, x = rem & 511;
  const __half* eb = edge16 + (size_t)b*PLANE;
  float s = 0.f;
#pragma unroll
  for (int dy=-1; dy<=1; ++dy)
#pragma unroll
    for (int dx=-1; dx<=1; ++dx) {
      int yy = y+dy, xx = x+dx;
      if (yy>=0 && yy<512 && xx>=0 && xx<512) s += __half2float(eb[(yy<<9)|xx]);
    }
  rnorm[id] = 1.f/(s*(1.f/9.f) + 1e-6f);
}

// ---------------- prep: compat == identity? ----------------
__global__ void k_flag(const float* __restrict__ compat, int* __restrict__ flag) {
  __shared__ int ok;
  if (threadIdx.x==0) ok = 1;
  __syncthreads();
  int bad = 0;
  for (int i = threadIdx.x; i < NC*NC; i += 256) {
    float exp = ((i/NC) == (i%NC)) ? 1.f : 0.f;
    if (compat[i] != exp) bad = 1;
  }
  if (bad) atomicAnd(&ok, 0);
  __syncthreads();
  if (threadIdx.x==0) flag[0] = ok;
}

// ---------------- prep: unary fp32 -> fp16 ----------------
__global__ __launch_bounds__(256)
void k_cvt(const float* __restrict__ u, __half* __restrict__ u16) {
  size_t q = (size_t)blockIdx.x*256 + threadIdx.x;
  float4 v = reinterpret_cast<const float4*>(u)[q];
  uint2 w; w.x = f2h(v.x, v.y); w.y = f2h(v.z, v.w);
  reinterpret_cast<uint2*>(u16)[q] = w;
}

// ---------------- Q0 = softmax(unary) -> fp16 ----------------
__global__ __launch_bounds__(256)
void k_softmax0(const float* __restrict__ unary, __half* __restrict__ Y) {
  int q = blockIdx.x*256 + threadIdx.x;           // quad id, [0, NPIX/4)
  int b = q >> 16;
  int rem = q & 65535;
  size_t base = (size_t)b*NC*(PLANE>>2) + rem;
  const float4* up = reinterpret_cast<const float4*>(unary);
  float v[NC][4];
  float mx0=-3e38f,mx1=-3e38f,mx2=-3e38f,mx3=-3e38f;
#pragma unroll
  for (int c=0;c<NC;++c) {
    float4 t = up[base + (size_t)c*(PLANE>>2)];
    v[c][0]=t.x; v[c][1]=t.y; v[c][2]=t.z; v[c][3]=t.w;
    mx0=fmaxf(mx0,t.x); mx1=fmaxf(mx1,t.y); mx2=fmaxf(mx2,t.z); mx3=fmaxf(mx3,t.w);
  }
  float s0=0,s1=0,s2=0,s3=0;
#pragma unroll
  for (int c=0;c<NC;++c) {
    float e0=__expf(v[c][0]-mx0), e1=__expf(v[c][1]-mx1);
    float e2=__expf(v[c][2]-mx2), e3=__expf(v[c][3]-mx3);
    v[c][0]=e0; v[c][1]=e1; v[c][2]=e2; v[c][3]=e3;
    s0+=e0; s1+=e1; s2+=e2; s3+=e3;
  }
  float r0=1.f/s0, r1=1.f/s1, r2=1.f/s2, r3=1.f/s3;
  uint2* yp = reinterpret_cast<uint2*>(Y);
#pragma unroll
  for (int c=0;c<NC;++c) {
    uint2 w; w.x=f2h(v[c][0]*r0, v[c][1]*r1); w.y=f2h(v[c][2]*r2, v[c][3]*r3);
    yp[base + (size_t)c*(PLANE>>2)] = w;
  }
}

// ---------------- fused CRF iteration ----------------
// R8: logits in LDS (fp32), NO long-lived register arrays.
// R6/R7 post-mortem: sched_barrier fences changed NOTHING (identical
// counters) -> the ALLOCATOR (not the scheduler) puts msgr[21][2] in scratch
// by policy for 512-thread blocks (R4's extra write = exactly 256 MiB =
// 1M threads x 256 B private segment). Fix: remove the array. l[c]=u[c]-msg[c]
// goes to LDS fp32 (l0/l1 [21][256], bank = tid%32, 2 lanes/bank = free).
// Tile 64x8, 256 threads, 2 px/thread; ping-pong channel staging; u[c]
// prefetched 1 ahead; running max online. Phase 2 = two tiny LDS passes.
// LDS 48.2 KB -> 3 blocks/CU. Live set ~55 VGPR -> nothing to spill.
// KEY PREDICTION: WRITE_SIZE 442368 -> ~86016 KiB (output only).

#define LOAD_U2(c, u0,u1) \
  float u0,u1; \
  if (U16) { unsigned int w_ = reinterpret_cast<const unsigned int*>(uptr)[hbase + (size_t)(c)*ch]; \
    float2 t_=h2f(w_); u0=t_.x; u1=t_.y; } \
  else { float2 v_ = reinterpret_cast<const float2*>(uptr)[hbase + (size_t)(c)*ch]; \
    u0=v_.x; u1=v_.y; }

#define CROW 72            // LDS row stride (halves) == staged cols
#define TROWS 12           // staged rows (8 tile + 4 halo)
#define CTILE (TROWS*CROW) // halves per channel buffer (864)

template<bool U16, bool OUTF32>
__global__ __launch_bounds__(256)
void k_iter(const __half* __restrict__ Qin,
            void* __restrict__ Qout,
            const void* __restrict__ uptr,
            const __half* __restrict__ edge16,
            const float* __restrict__ rnorm,
            const float* __restrict__ swp,
            const float* __restrict__ bwp,
            const float* __restrict__ compat,
            const int* __restrict__ flag)
{
  __shared__ __half qbuf[2][CTILE];   // 2 x 12 x 72 halves = 3456 B
  __shared__ __half et[CTILE];        //     12 x 72 halves = 1728 B
  __shared__ float l0[NC][256];       // 21504 B
  __shared__ float l1[NC][256];       // 21504 B   total 48192 B

  const int tid = threadIdx.x;
  const int tx = tid & 31;        // 32 threads across 64 px, 2 px each
  const int ty = tid >> 5;        // 8 rows
  const int x0 = blockIdx.x << 6;
  const int y0 = blockIdx.y << 3;
  const int b  = blockIdx.z;

  // ---- staging slot: 12 rows x 18 uint2 (4 halves) = 216 slots ----
  const int slot = tid;
  const int sr = slot / 18;
  const int si = slot - sr*18;
  const int sy = y0 - 2 + sr;                 // rows y0-2 .. y0+9
  const int sx = x0 - 4 + (si<<2);            // cols x0-4 .. x0+67, step 4
  const bool sact = (slot < 216);
  const bool sval = sact && (sy>=0) && (sy<512) && (sx>=0) && (sx<512);
  const int  goff = (sy<<9) + sx;             // halves into plane (use iff sval)
  const int  loff = sr*CROW + (si<<2);        // halves into tile

  const int gy  = y0 + ty;
  const int gx  = x0 + (tx<<1);
  const int pix = (gy<<9) | gx;

  // early independent loads (overlap with staging latency)
  const float2 rn = *reinterpret_cast<const float2*>(rnorm + (size_t)b*PLANE + pix);
  const float sw  = fmaxf(swp[0], 0.f);
  const float bw  = fmaxf(bwp[0], 0.f);
  const int fl = flag[0];

  const size_t hbase = (((size_t)b*NC*PLANE) + (size_t)pix) >> 1;  // uint / float2 units
  const size_t ch = PLANE >> 1;

  // ---- prologue: stage edge tile + channel 0 tile + u[0], one barrier ----
  const __half* qb = Qin + (size_t)b*NC*PLANE;
  unsigned int ucur = 0; float2 ufcur = make_float2(0.f,0.f);
  if (U16) ucur = reinterpret_cast<const unsigned int*>(uptr)[hbase];
  else     ufcur = reinterpret_cast<const float2*>(uptr)[hbase];
  {
    const __half* ep = edge16 + (size_t)b*PLANE;
    uint2 we = make_uint2(0u, 0u);
    uint2 w0 = make_uint2(0u, 0u);
    if (sval) {
      we = *reinterpret_cast<const uint2*>(ep + goff);
      w0 = *reinterpret_cast<const uint2*>(qb + goff);
    }
    if (sact) {
      *reinterpret_cast<uint2*>(et + loff) = we;
      *reinterpret_cast<uint2*>(qbuf[0] + loff) = w0;
    }
  }
  __syncthreads();

  const float csw = sw * 0.04f;          // sw/25
  const float b9  = bw * (1.f/9.f);      // bw/9
  const float cb0 = b9*rn.x, cb1 = b9*rn.y;

  const int lx2 = (tx<<1) + 2;           // LDS col of gx-2 (staged region shift)

  // hoist edge window into registers once (channel-invariant):
  // rows ty+1..ty+3, global cols gx-1..gx+2 = staged cols lx2+1..lx2+4
  float ew[3][4];
#pragma unroll
  for (int dy=0;dy<3;++dy) {
    const unsigned int* erow = reinterpret_cast<const unsigned int*>(et + (ty+1+dy)*CROW + lx2);
    float2 e0 = h2f(erow[0]);
    float2 e1 = h2f(erow[1]);
    float2 e2 = h2f(erow[2]);
    ew[dy][0]=e0.y; ew[dy][1]=e1.x; ew[dy][2]=e1.y; ew[dy][3]=e2.x;
  }

  // ---- pipelined channel loop: prefetch c+1 | compute c | l -> LDS ----
  float mx0=-3e38f, mx1=-3e38f;

#pragma unroll
  for (int c=0;c<NC;++c) {
    // issue next channel's staging + unary loads early (hidden under compute)
    uint2 wn = make_uint2(0u, 0u);
    unsigned int un = 0; float2 unf = make_float2(0.f,0.f);
    if (c+1 < NC) {
      if (sval) wn = *reinterpret_cast<const uint2*>(qb + (size_t)(c+1)*PLANE + goff);
      if (U16) un = reinterpret_cast<const unsigned int*>(uptr)[hbase + (size_t)(c+1)*ch];
      else     unf = reinterpret_cast<const float2*>(uptr)[hbase + (size_t)(c+1)*ch];
    }

    // compute msg[c] from qbuf[c&1] (pure LDS)
    const __half* qrow0 = qbuf[c&1] + ty*CROW + lx2;
    float cs0=0,cs1=0,cs2=0,cs3=0,cs4=0,cs5=0;
    float ce0=0,ce1=0,ce2=0,ce3=0;
#pragma unroll
    for (int dy=0;dy<5;++dy) {
      const unsigned int* qrow = reinterpret_cast<const unsigned int*>(qrow0 + dy*CROW);
      float2 t0 = h2f(qrow[0]);   // gx-2, gx-1
      float2 t1 = h2f(qrow[1]);   // gx  , gx+1
      float2 t2 = h2f(qrow[2]);   // gx+2, gx+3
      cs0+=t0.x; cs1+=t0.y; cs2+=t1.x; cs3+=t1.y; cs4+=t2.x; cs5+=t2.y;
      if (dy>=1 && dy<=3) {
        ce0 += t0.y*ew[dy-1][0];   // gx-1
        ce1 += t1.x*ew[dy-1][1];   // gx
        ce2 += t1.y*ew[dy-1][2];   // gx+1
        ce3 += t2.x*ew[dy-1][3];   // gx+2
      }
    }
    float v0 = cs0+cs1+cs2+cs3+cs4;      // 5-wide window @ gx
    float v1 = v0 - cs0 + cs5;           // @ gx+1
    float w0 = ce0+ce1+ce2;              // 3-wide window @ gx
    float w1 = ce1+ce2+ce3;              // @ gx+1
    float m0 = csw*v0 + cb0*w0;
    float m1 = csw*v1 + cb1*w1;

    // l = u - msg (identity path) or raw msg (general path); store to LDS
    float u0c, u1c;
    if (U16) { float2 t = h2f(ucur); u0c=t.x; u1c=t.y; }
    else     { u0c=ufcur.x; u1c=ufcur.y; }
    float lv0, lv1;
    if (fl) {
      lv0 = u0c - m0; lv1 = u1c - m1;
      mx0 = fmaxf(mx0, lv0); mx1 = fmaxf(mx1, lv1);
    } else {
      lv0 = m0; lv1 = m1;
    }
    l0[c][tid] = lv0;
    l1[c][tid] = lv1;

    // commit next channel's tile to the other buffer, then sync
    if (c+1 < NC) {
      if (sact) *reinterpret_cast<uint2*>(qbuf[(c+1)&1] + loff) = wn;
      __syncthreads();
    }
    ucur = un; ufcur = unf;
  }

  // ---- phase 2: softmax over channels from LDS (thread-private slots) ----
  if (fl) {   // identity compat fast path
    float s0=0.f, s1=0.f;
#pragma unroll
    for (int c=0;c<NC;++c) {
      float e0=__expf(l0[c][tid]-mx0), e1=__expf(l1[c][tid]-mx1);
      l0[c][tid]=e0; l1[c][tid]=e1;
      s0+=e0; s1+=e1;
    }
    float r0=1.f/s0, r1=1.f/s1;
#pragma unroll
    for (int c=0;c<NC;++c) {
      float o0=l0[c][tid]*r0, o1=l1[c][tid]*r1;
      if (OUTF32) {
        reinterpret_cast<float2*>(Qout)[hbase + (size_t)c*ch] = make_float2(o0,o1);
      } else {
        reinterpret_cast<unsigned int*>(Qout)[hbase + (size_t)c*ch] = f2h(o0,o1);
      }
    }
  } else {    // general compat: msg values in LDS, recompute logits per pass
    float mxa=-3e38f, mxb=-3e38f;
#pragma unroll 1
    for (int c=0;c<NC;++c) {
      float a0=0.f,a1=0.f;
#pragma unroll
      for (int d=0;d<NC;++d) { float cf=compat[c*NC+d]; a0+=cf*l0[d][tid]; a1+=cf*l1[d][tid]; }
      LOAD_U2(c, u0,u1)
      mxa=fmaxf(mxa,u0-a0); mxb=fmaxf(mxb,u1-a1);
    }
    float s0=0.f,s1=0.f;
#pragma unroll 1
    for (int c=0;c<NC;++c) {
      float a0=0.f,a1=0.f;
#pragma unroll
      for (int d=0;d<NC;++d) { float cf=compat[c*NC+d]; a0+=cf*l0[d][tid]; a1+=cf*l1[d][tid]; }
      LOAD_U2(c, u0,u1)
      s0+=__expf(u0-a0-mxa); s1+=__expf(u1-a1-mxb);
    }
    float r0=1.f/s0, r1=1.f/s1;
#pragma unroll 1
    for (int c=0;c<NC;++c) {
      float a0=0.f,a1=0.f;
#pragma unroll
      for (int d=0;d<NC;++d) { float cf=compat[c*NC+d]; a0+=cf*l0[d][tid]; a1+=cf*l1[d][tid]; }
      LOAD_U2(c, u0,u1)
      float o0=__expf(u0-a0-mxa)*r0, o1=__expf(u1-a1-mxb)*r1;
      if (OUTF32) {
        reinterpret_cast<float2*>(Qout)[hbase + (size_t)c*ch] = make_float2(o0,o1);
      } else {
        reinterpret_cast<unsigned int*>(Qout)[hbase + (size_t)c*ch] = f2h(o0,o1);
      }
    }
  }
}

extern "C" void kernel_launch(void* const* d_in, const int* in_sizes, int n_in,
                              void* d_out, int out_size, void* d_ws, size_t ws_size,
                              hipStream_t stream)
{
  const float* unary  = (const float*)d_in[0];
  const float* image  = (const float*)d_in[1];
  const float* compat = (const float*)d_in[2];
  const float* swp    = (const float*)d_in[3];
  const float* bwp    = (const float*)d_in[4];

  // ws layout (bytes): X fp16 Q buffer | edge16 | rnorm | flag | (opt) u16
  char* ws = (char*)d_ws;
  __half* X      = (__half*)(ws + 0);            // 88,080,384 B
  __half* edge16 = (__half*)(ws + 88080384);     //  4,194,304 B
  float*  rnorm  = (float*) (ws + 92274688);     //  8,388,608 B
  int*    flag   = (int*)   (ws + 100663296);    //        256 B
  __half* u16    = (__half*)(ws + 100663552);    // 88,080,384 B (optional)
  if (ws_size < (size_t)100663552) return;       // cannot run without scratch
  const bool use_u16 = (ws_size >= (size_t)188743936);

  __half* Y  = (__half*)d_out;   // d_out doubles as fp16 scratch during iters
  float* out = (float*)d_out;

  k_edge   <<<dim3(8192), dim3(256), 0, stream>>>(image, edge16);
  k_rnorm  <<<dim3(8192), dim3(256), 0, stream>>>(edge16, rnorm);
  k_flag   <<<dim3(1),    dim3(256), 0, stream>>>(compat, flag);
  if (use_u16) k_cvt<<<dim3(43008), dim3(256), 0, stream>>>(unary, u16);
  k_softmax0<<<dim3(2048), dim3(256), 0, stream>>>(unary, Y);

  const void* up = use_u16 ? (const void*)u16 : (const void*)unary;
  dim3 gi(8, 64, NB), bi(256);
  // Q0 -> Y(d_out,fp16); odd iters Y->X; even iters X->Y; iter10 X -> d_out fp32
  for (int it = 1; it <= 10; ++it) {
    const __half* qin = (it & 1) ? Y : X;
    if (it == 10) {
      if (use_u16) k_iter<true , true ><<<gi,bi,0,stream>>>(qin,(void*)out,up,edge16,rnorm,swp,bwp,compat,flag);
      else         k_iter<false, true ><<<gi,bi,0,stream>>>(qin,(void*)out,up,edge16,rnorm,swp,bwp,compat,flag);
    } else {
      void* qout = (it & 1) ? (void*)X : (void*)Y;
      if (use_u16) k_iter<true , false><<<gi,bi,0,stream>>>(qin,qout,up,edge16,rnorm,swp,bwp,compat,flag);
      else         k_iter<false, false><<<gi,bi,0,stream>>>(qin,qout,up,edge16,rnorm,swp,bwp,compat,flag);
    }
  }
}

// Round 9
// 1173.185 us; speedup vs baseline: 4.9512x; 1.1177x over previous
//
#include <hip/hip_runtime.h>
#include <hip/hip_fp16.h>

#define PLANE 262144   // 512*512
#define NC 21
#define NB 8
#define NPIX (NB*PLANE)

__device__ __forceinline__ float2 h2f(unsigned int u) {
  union { unsigned int u; __half2 h; } x; x.u = u;
  return __half22float2(x.h);
}
__device__ __forceinline__ unsigned int f2h(float a, float b) {
  union { unsigned int u; __half2 h; } x;
  x.h = __floats2half2_rn(a, b);
  return x.u;
}

// ---------------- prep: edge = exp(-|sobel(gray)|) ----------------
__global__ __launch_bounds__(256)
void k_edge(const float* __restrict__ img, __half* __restrict__ edge16) {
  int id = blockIdx.x*256 + threadIdx.x;
  int b = id >> 18;
  int rem = id & (PLANE-1);
  int y = rem >> 9, x = rem & 511;
  const float* ib = img + (size_t)b*3*PLANE;
  float g[3][3];
#pragma unroll
  for (int dy=0; dy<3; ++dy)
#pragma unroll
    for (int dx=0; dx<3; ++dx) {
      int yy = y+dy-1, xx = x+dx-1;
      float v = 0.f;
      if (yy>=0 && yy<512 && xx>=0 && xx<512) {
        int o = (yy<<9)|xx;
        v = 0.299f*ib[o] + 0.587f*ib[o+PLANE] + 0.114f*ib[o+2*PLANE];
      }
      g[dy][dx]=v;
    }
  float gxv = (g[0][2]-g[0][0]) + 2.f*(g[1][2]-g[1][0]) + (g[2][2]-g[2][0]);
  float gyv = (g[2][0]-g[0][0]) + 2.f*(g[2][1]-g[0][1]) + (g[2][2]-g[0][2]);
  float mag = sqrtf(gxv*gxv + gyv*gyv + 1e-6f);
  edge16[id] = __float2half(__expf(-mag));
}

// ---------------- prep: rnorm = 1/(avgpool3(edge)+1e-6) ----------------
__global__ __launch_bounds__(256)
void k_rnorm(const __half* __restrict__ edge16, float* __restrict__ rnorm) {
  int id = blockIdx.x*256 + threadIdx.x;
  int b = id >> 18;
  int rem = id & (PLANE-1);
  int y = rem >> 9, x = rem & 511;
  const __half* eb = edge16 + (size_t)b*PLANE;
  float s = 0.f;
#pragma unroll
  for (int dy=-1; dy<=1; ++dy)
#pragma unroll
    for (int dx=-1; dx<=1; ++dx) {
      int yy = y+dy, xx = x+dx;
      if (yy>=0 && yy<512 && xx>=0 && xx<512) s += __half2float(eb[(yy<<9)|xx]);
    }
  rnorm[id] = 1.f/(s*(1.f/9.f) + 1e-6f);
}

// ---------------- prep: compat == identity? ----------------
__global__ void k_flag(const float* __restrict__ compat, int* __restrict__ flag) {
  __shared__ int ok;
  if (threadIdx.x==0) ok = 1;
  __syncthreads();
  int bad = 0;
  for (int i = threadIdx.x; i < NC*NC; i += 256) {
    float exp = ((i/NC) == (i%NC)) ? 1.f : 0.f;
    if (compat[i] != exp) bad = 1;
  }
  if (bad) atomicAnd(&ok, 0);
  __syncthreads();
  if (threadIdx.x==0) flag[0] = ok;
}

// ---------------- prep: unary fp32 -> fp16 ----------------
__global__ __launch_bounds__(256)
void k_cvt(const float* __restrict__ u, __half* __restrict__ u16) {
  size_t q = (size_t)blockIdx.x*256 + threadIdx.x;
  float4 v = reinterpret_cast<const float4*>(u)[q];
  uint2 w; w.x = f2h(v.x, v.y); w.y = f2h(v.z, v.w);
  reinterpret_cast<uint2*>(u16)[q] = w;
}

// ---------------- Q0 = softmax(unary) -> fp16 ----------------
__global__ __launch_bounds__(256)
void k_softmax0(const float* __restrict__ unary, __half* __restrict__ Y) {
  int q = blockIdx.x*256 + threadIdx.x;           // quad id, [0, NPIX/4)
  int b = q >> 16;
  int rem = q & 65535;
  size_t base = (size_t)b*NC*(PLANE>>2) + rem;
  const float4* up = reinterpret_cast<const float4*>(unary);
  float v[NC][4];
  float mx0=-3e38f,mx1=-3e38f,mx2=-3e38f,mx3=-3e38f;
#pragma unroll
  for (int c=0;c<NC;++c) {
    float4 t = up[base + (size_t)c*(PLANE>>2)];
    v[c][0]=t.x; v[c][1]=t.y; v[c][2]=t.z; v[c][3]=t.w;
    mx0=fmaxf(mx0,t.x); mx1=fmaxf(mx1,t.y); mx2=fmaxf(mx2,t.z); mx3=fmaxf(mx3,t.w);
  }
  float s0=0,s1=0,s2=0,s3=0;
#pragma unroll
  for (int c=0;c<NC;++c) {
    float e0=__expf(v[c][0]-mx0), e1=__expf(v[c][1]-mx1);
    float e2=__expf(v[c][2]-mx2), e3=__expf(v[c][3]-mx3);
    v[c][0]=e0; v[c][1]=e1; v[c][2]=e2; v[c][3]=e3;
    s0+=e0; s1+=e1; s2+=e2; s3+=e3;
  }
  float r0=1.f/s0, r1=1.f/s1, r2=1.f/s2, r3=1.f/s3;
  uint2* yp = reinterpret_cast<uint2*>(Y);
#pragma unroll
  for (int c=0;c<NC;++c) {
    uint2 w; w.x=f2h(v[c][0]*r0, v[c][1]*r1); w.y=f2h(v[c][2]*r2, v[c][3]*r3);
    yp[base + (size_t)c*(PLANE>>2)] = w;
  }
}

// ---------------- fused CRF iteration ----------------
// R9 = R8 + packed-fp16 vertical sums + channel-pair staging.
// R8 post-mortem: WRITE = exactly 1.0x output -> spills GONE (LDS-logit
// design works; the R4-R7 spills were allocator policy on long-lived arrays).
// New bound: VALU (53% busy, 61us of 116us; HBM floor 27us, LDS 24us).
// Changes: (1) vertical column sums via __hadd2 (v_pk_add_f16): 15 pk_add +
// 6 cvt replaces 30 cvt + 30 add per channel (~-35% VALU). Edge term stays
// fp32 (cb up to ~10x rnorm makes fp16 unsafe there; cs error ~2e-4 logit).
// (2) stage channels in PAIRS (qbuf[2][2]) -> 11 barriers instead of 21,
// 2x prefetch distance. (3) logits stored as float2 (b64 LDS ops).
// KEY INVARIANT: WRITE_SIZE must stay 86016 KiB (no spills).

#define LOAD_U2(c, u0,u1) \
  float u0,u1; \
  if (U16) { unsigned int w_ = reinterpret_cast<const unsigned int*>(uptr)[hbase + (size_t)(c)*ch]; \
    float2 t_=h2f(w_); u0=t_.x; u1=t_.y; } \
  else { float2 v_ = reinterpret_cast<const float2*>(uptr)[hbase + (size_t)(c)*ch]; \
    u0=v_.x; u1=v_.y; }

#define CROW 72            // LDS row stride (halves) == staged cols
#define TROWS 12           // staged rows (8 tile + 4 halo)
#define CTILE (TROWS*CROW) // halves per channel buffer (864)

// compute one channel's message from LDS tile `buf`, fold unary, store logit
#define COMPUTE_CH(c, buf, uu, uf) do { \
    const __half* qrow0_ = (buf) + ty*CROW + lx2; \
    __half2 a0_ = __float2half2_rn(0.f); \
    __half2 a1_ = a0_, a2_ = a0_; \
    float ce0=0.f,ce1=0.f,ce2=0.f,ce3=0.f; \
    _Pragma("unroll") \
    for (int dy=0;dy<5;++dy) { \
      const __half2* qrow = reinterpret_cast<const __half2*>(qrow0_ + dy*CROW); \
      __half2 q0=qrow[0], q1=qrow[1], q2=qrow[2]; \
      a0_ = __hadd2(a0_, q0); a1_ = __hadd2(a1_, q1); a2_ = __hadd2(a2_, q2); \
      if (dy>=1 && dy<=3) { \
        ce0 += __high2float(q0)*ew[dy-1][0]; \
        ce1 += __low2float (q1)*ew[dy-1][1]; \
        ce2 += __high2float(q1)*ew[dy-1][2]; \
        ce3 += __low2float (q2)*ew[dy-1][3]; \
      } \
    } \
    float cs0=__low2float(a0_), cs1=__high2float(a0_); \
    float cs2=__low2float(a1_), cs3=__high2float(a1_); \
    float cs4=__low2float(a2_), cs5=__high2float(a2_); \
    float v0 = cs0+cs1+cs2+cs3+cs4; \
    float v1 = v0 - cs0 + cs5; \
    float w0 = ce0+ce1+ce2; \
    float w1 = ce1+ce2+ce3; \
    float m0 = csw*v0 + cb0*w0; \
    float m1 = csw*v1 + cb1*w1; \
    float u0c,u1c; \
    if (U16) { float2 t_=h2f(uu); u0c=t_.x; u1c=t_.y; } \
    else     { u0c=(uf).x; u1c=(uf).y; } \
    float lv0, lv1; \
    if (fl) { lv0=u0c-m0; lv1=u1c-m1; mx0=fmaxf(mx0,lv0); mx1=fmaxf(mx1,lv1); } \
    else    { lv0=m0; lv1=m1; } \
    lsm[c][tid] = make_float2(lv0, lv1); \
  } while(0)

template<bool U16, bool OUTF32>
__global__ __launch_bounds__(256)
void k_iter(const __half* __restrict__ Qin,
            void* __restrict__ Qout,
            const void* __restrict__ uptr,
            const __half* __restrict__ edge16,
            const float* __restrict__ rnorm,
            const float* __restrict__ swp,
            const float* __restrict__ bwp,
            const float* __restrict__ compat,
            const int* __restrict__ flag)
{
  __shared__ __half qbuf[2][2][CTILE]; // pair parity x ch-in-pair: 6912 B
  __shared__ __half et[CTILE];         // 1728 B
  __shared__ float2 lsm[NC][256];      // 43008 B    total 51648 B

  const int tid = threadIdx.x;
  const int tx = tid & 31;        // 32 threads across 64 px, 2 px each
  const int ty = tid >> 5;        // 8 rows
  const int x0 = blockIdx.x << 6;
  const int y0 = blockIdx.y << 3;
  const int b  = blockIdx.z;

  // ---- staging slot: 12 rows x 18 uint2 (4 halves) = 216 slots ----
  const int slot = tid;
  const int sr = slot / 18;
  const int si = slot - sr*18;
  const int sy = y0 - 2 + sr;                 // rows y0-2 .. y0+9
  const int sx = x0 - 4 + (si<<2);            // cols x0-4 .. x0+67, step 4
  const bool sact = (slot < 216);
  const bool sval = sact && (sy>=0) && (sy<512) && (sx>=0) && (sx<512);
  const int  goff = (sy<<9) + sx;             // halves into plane (use iff sval)
  const int  loff = sr*CROW + (si<<2);        // halves into tile

  const int gy  = y0 + ty;
  const int gx  = x0 + (tx<<1);
  const int pix = (gy<<9) | gx;

  // early independent loads (overlap with staging latency)
  const float2 rn = *reinterpret_cast<const float2*>(rnorm + (size_t)b*PLANE + pix);
  const float sw  = fmaxf(swp[0], 0.f);
  const float bw  = fmaxf(bwp[0], 0.f);
  const int fl = flag[0];

  const size_t hbase = (((size_t)b*NC*PLANE) + (size_t)pix) >> 1;  // uint / float2 units
  const size_t ch = PLANE >> 1;

  // ---- prologue: u[0],u[1] + edge tile + ch0/ch1 tiles, one barrier ----
  const __half* qb = Qin + (size_t)b*NC*PLANE;
  unsigned int uc0=0, uc1=0; float2 uf0=make_float2(0.f,0.f), uf1=uf0;
  if (U16) {
    uc0 = reinterpret_cast<const unsigned int*>(uptr)[hbase];
    uc1 = reinterpret_cast<const unsigned int*>(uptr)[hbase + ch];
  } else {
    uf0 = reinterpret_cast<const float2*>(uptr)[hbase];
    uf1 = reinterpret_cast<const float2*>(uptr)[hbase + ch];
  }
  {
    const __half* ep = edge16 + (size_t)b*PLANE;
    uint2 we = make_uint2(0u,0u), w0 = we, w1 = we;
    if (sval) {
      we = *reinterpret_cast<const uint2*>(ep + goff);
      w0 = *reinterpret_cast<const uint2*>(qb + goff);
      w1 = *reinterpret_cast<const uint2*>(qb + PLANE + goff);
    }
    if (sact) {
      *reinterpret_cast<uint2*>(et + loff) = we;
      *reinterpret_cast<uint2*>(qbuf[0][0] + loff) = w0;
      *reinterpret_cast<uint2*>(qbuf[0][1] + loff) = w1;
    }
  }
  __syncthreads();

  const float csw = sw * 0.04f;          // sw/25
  const float b9  = bw * (1.f/9.f);      // bw/9
  const float cb0 = b9*rn.x, cb1 = b9*rn.y;

  const int lx2 = (tx<<1) + 2;           // LDS col of gx-2 (staged region shift)

  // hoist edge window into registers once (channel-invariant):
  // rows ty+1..ty+3, global cols gx-1..gx+2 = staged cols lx2+1..lx2+4
  float ew[3][4];
#pragma unroll
  for (int dy=0;dy<3;++dy) {
    const unsigned int* erow = reinterpret_cast<const unsigned int*>(et + (ty+1+dy)*CROW + lx2);
    float2 e0 = h2f(erow[0]);
    float2 e1 = h2f(erow[1]);
    float2 e2 = h2f(erow[2]);
    ew[dy][0]=e0.y; ew[dy][1]=e1.x; ew[dy][2]=e1.y; ew[dy][3]=e2.x;
  }

  // ---- pipelined pair loop: prefetch pair cp+1 | compute pair cp ----
  float mx0=-3e38f, mx1=-3e38f;

#pragma unroll
  for (int cp=0; cp<11; ++cp) {
    const int c0 = 2*cp, c1 = 2*cp+1;

    // prefetch next pair's tiles + unary (hidden under compute)
    uint2 wn0 = make_uint2(0u,0u), wn1 = wn0;
    unsigned int un0=0, un1=0; float2 unf0=make_float2(0.f,0.f), unf1=unf0;
    if (c0+2 < NC) {
      if (sval) wn0 = *reinterpret_cast<const uint2*>(qb + (size_t)(c0+2)*PLANE + goff);
      if (U16) un0 = reinterpret_cast<const unsigned int*>(uptr)[hbase + (size_t)(c0+2)*ch];
      else     unf0 = reinterpret_cast<const float2*>(uptr)[hbase + (size_t)(c0+2)*ch];
    }
    if (c1+2 < NC) {
      if (sval) wn1 = *reinterpret_cast<const uint2*>(qb + (size_t)(c1+2)*PLANE + goff);
      if (U16) un1 = reinterpret_cast<const unsigned int*>(uptr)[hbase + (size_t)(c1+2)*ch];
      else     unf1 = reinterpret_cast<const float2*>(uptr)[hbase + (size_t)(c1+2)*ch];
    }

    COMPUTE_CH(c0, qbuf[cp&1][0], uc0, uf0);
    if (c1 < NC) COMPUTE_CH(c1, qbuf[cp&1][1], uc1, uf1);

    if (c0+2 < NC) {
      if (sact) {
        *reinterpret_cast<uint2*>(qbuf[(cp+1)&1][0] + loff) = wn0;
        if (c1+2 < NC) *reinterpret_cast<uint2*>(qbuf[(cp+1)&1][1] + loff) = wn1;
      }
      __syncthreads();
    }
    uc0=un0; uc1=un1; uf0=unf0; uf1=unf1;
  }

  // ---- phase 2: softmax over channels from LDS (thread-private slots) ----
  if (fl) {   // identity compat fast path
    float s0=0.f, s1=0.f;
#pragma unroll
    for (int c=0;c<NC;++c) {
      float2 lv = lsm[c][tid];
      float e0=__expf(lv.x-mx0), e1=__expf(lv.y-mx1);
      lsm[c][tid]=make_float2(e0,e1);
      s0+=e0; s1+=e1;
    }
    float r0=1.f/s0, r1=1.f/s1;
#pragma unroll
    for (int c=0;c<NC;++c) {
      float2 ev = lsm[c][tid];
      float o0=ev.x*r0, o1=ev.y*r1;
      if (OUTF32) {
        reinterpret_cast<float2*>(Qout)[hbase + (size_t)c*ch] = make_float2(o0,o1);
      } else {
        reinterpret_cast<unsigned int*>(Qout)[hbase + (size_t)c*ch] = f2h(o0,o1);
      }
    }
  } else {    // general compat: msg values in LDS, recompute logits per pass
    float mxa=-3e38f, mxb=-3e38f;
#pragma unroll 1
    for (int c=0;c<NC;++c) {
      float a0=0.f,a1=0.f;
#pragma unroll
      for (int d=0;d<NC;++d) { float cf=compat[c*NC+d]; float2 lv=lsm[d][tid]; a0+=cf*lv.x; a1+=cf*lv.y; }
      LOAD_U2(c, u0,u1)
      mxa=fmaxf(mxa,u0-a0); mxb=fmaxf(mxb,u1-a1);
    }
    float s0=0.f,s1=0.f;
#pragma unroll 1
    for (int c=0;c<NC;++c) {
      float a0=0.f,a1=0.f;
#pragma unroll
      for (int d=0;d<NC;++d) { float cf=compat[c*NC+d]; float2 lv=lsm[d][tid]; a0+=cf*lv.x; a1+=cf*lv.y; }
      LOAD_U2(c, u0,u1)
      s0+=__expf(u0-a0-mxa); s1+=__expf(u1-a1-mxb);
    }
    float r0=1.f/s0, r1=1.f/s1;
#pragma unroll 1
    for (int c=0;c<NC;++c) {
      float a0=0.f,a1=0.f;
#pragma unroll
      for (int d=0;d<NC;++d) { float cf=compat[c*NC+d]; float2 lv=lsm[d][tid]; a0+=cf*lv.x; a1+=cf*lv.y; }
      LOAD_U2(c, u0,u1)
      float o0=__expf(u0-a0-mxa)*r0, o1=__expf(u1-a1-mxb)*r1;
      if (OUTF32) {
        reinterpret_cast<float2*>(Qout)[hbase + (size_t)c*ch] = make_float2(o0,o1);
      } else {
        reinterpret_cast<unsigned int*>(Qout)[hbase + (size_t)c*ch] = f2h(o0,o1);
      }
    }
  }
}

extern "C" void kernel_launch(void* const* d_in, const int* in_sizes, int n_in,
                              void* d_out, int out_size, void* d_ws, size_t ws_size,
                              hipStream_t stream)
{
  const float* unary  = (const float*)d_in[0];
  const float* image  = (const float*)d_in[1];
  const float* compat = (const float*)d_in[2];
  const float* swp    = (const float*)d_in[3];
  const float* bwp    = (const float*)d_in[4];

  // ws layout (bytes): X fp16 Q buffer | edge16 | rnorm | flag | (opt) u16
  char* ws = (char*)d_ws;
  __half* X      = (__half*)(ws + 0);            // 88,080,384 B
  __half* edge16 = (__half*)(ws + 88080384);     //  4,194,304 B
  float*  rnorm  = (float*) (ws + 92274688);     //  8,388,608 B
  int*    flag   = (int*)   (ws + 100663296);    //        256 B
  __half* u16    = (__half*)(ws + 100663552);    // 88,080,384 B (optional)
  if (ws_size < (size_t)100663552) return;       // cannot run without scratch
  const bool use_u16 = (ws_size >= (size_t)188743936);

  __half* Y  = (__half*)d_out;   // d_out doubles as fp16 scratch during iters
  float* out = (float*)d_out;

  k_edge   <<<dim3(8192), dim3(256), 0, stream>>>(image, edge16);
  k_rnorm  <<<dim3(8192), dim3(256), 0, stream>>>(edge16, rnorm);
  k_flag   <<<dim3(1),    dim3(256), 0, stream>>>(compat, flag);
  if (use_u16) k_cvt<<<dim3(43008), dim3(256), 0, stream>>>(unary, u16);
  k_softmax0<<<dim3(2048), dim3(256), 0, stream>>>(unary, Y);

  const void* up = use_u16 ? (const void*)u16 : (const void*)unary;
  dim3 gi(8, 64, NB), bi(256);
  // Q0 -> Y(d_out,fp16); odd iters Y->X; even iters X->Y; iter10 X -> d_out fp32
  for (int it = 1; it <= 10; ++it) {
    const __half* qin = (it & 1) ? Y : X;
    if (it == 10) {
      if (use_u16) k_iter<true , true ><<<gi,bi,0,stream>>>(qin,(void*)out,up,edge16,rnorm,swp,bwp,compat,flag);
      else         k_iter<false, true ><<<gi,bi,0,stream>>>(qin,(void*)out,up,edge16,rnorm,swp,bwp,compat,flag);
    } else {
      void* qout = (it & 1) ? (void*)X : (void*)Y;
      if (use_u16) k_iter<true , false><<<gi,bi,0,stream>>>(qin,qout,up,edge16,rnorm,swp,bwp,compat,flag);
      else         k_iter<false, false><<<gi,bi,0,stream>>>(qin,qout,up,edge16,rnorm,swp,bwp,compat,flag);
    }
  }
}

// Round 10
// 1103.030 us; speedup vs baseline: 5.2661x; 1.0636x over previous
//
#include <hip/hip_runtime.h>
#include <hip/hip_fp16.h>

#define PLANE 262144   // 512*512
#define NC 21
#define NB 8
#define NPIX (NB*PLANE)

__device__ __forceinline__ float2 h2f(unsigned int u) {
  union { unsigned int u; __half2 h; } x; x.u = u;
  return __half22float2(x.h);
}
__device__ __forceinline__ unsigned int f2h(float a, float b) {
  union { unsigned int u; __half2 h; } x;
  x.h = __floats2half2_rn(a, b);
  return x.u;
}

// ---------------- prep: edge = exp(-|sobel(gray)|) ----------------
__global__ __launch_bounds__(256)
void k_edge(const float* __restrict__ img, __half* __restrict__ edge16) {
  int id = blockIdx.x*256 + threadIdx.x;
  int b = id >> 18;
  int rem = id & (PLANE-1);
  int y = rem >> 9, x = rem & 511;
  const float* ib = img + (size_t)b*3*PLANE;
  float g[3][3];
#pragma unroll
  for (int dy=0; dy<3; ++dy)
#pragma unroll
    for (int dx=0; dx<3; ++dx) {
      int yy = y+dy-1, xx = x+dx-1;
      float v = 0.f;
      if (yy>=0 && yy<512 && xx>=0 && xx<512) {
        int o = (yy<<9)|xx;
        v = 0.299f*ib[o] + 0.587f*ib[o+PLANE] + 0.114f*ib[o+2*PLANE];
      }
      g[dy][dx]=v;
    }
  float gxv = (g[0][2]-g[0][0]) + 2.f*(g[1][2]-g[1][0]) + (g[2][2]-g[2][0]);
  float gyv = (g[2][0]-g[0][0]) + 2.f*(g[2][1]-g[0][1]) + (g[2][2]-g[0][2]);
  float mag = sqrtf(gxv*gxv + gyv*gyv + 1e-6f);
  edge16[id] = __float2half(__expf(-mag));
}

// ---------------- prep: rnorm = 1/(avgpool3(edge)+1e-6) ----------------
__global__ __launch_bounds__(256)
void k_rnorm(const __half* __restrict__ edge16, float* __restrict__ rnorm) {
  int id = blockIdx.x*256 + threadIdx.x;
  int b = id >> 18;
  int rem = id & (PLANE-1);
  int y = rem >> 9, x = rem & 511;
  const __half* eb = edge16 + (size_t)b*PLANE;
  float s = 0.f;
#pragma unroll
  for (int dy=-1; dy<=1; ++dy)
#pragma unroll
    for (int dx=-1; dx<=1; ++dx) {
      int yy = y+dy, xx = x+dx;
      if (yy>=0 && yy<512 && xx>=0 && xx<512) s += __half2float(eb[(yy<<9)|xx]);
    }
  rnorm[id] = 1.f/(s*(1.f/9.f) + 1e-6f);
}

// ---------------- prep: compat == identity? ----------------
__global__ void k_flag(const float* __restrict__ compat, int* __restrict__ flag) {
  __shared__ int ok;
  if (threadIdx.x==0) ok = 1;
  __syncthreads();
  int bad = 0;
  for (int i = threadIdx.x; i < NC*NC; i += 256) {
    float exp = ((i/NC) == (i%NC)) ? 1.f : 0.f;
    if (compat[i] != exp) bad = 1;
  }
  if (bad) atomicAnd(&ok, 0);
  __syncthreads();
  if (threadIdx.x==0) flag[0] = ok;
}

// ---------------- fused prep: u16 = fp16(unary); Y = softmax(unary) ----------------
// R10: fuses k_cvt + k_softmax0 (both re-read unary 176 MB; fusion saves one
// full read ~28us + a launch).
template<bool WU16>
__global__ __launch_bounds__(256)
void k_prep0(const float* __restrict__ unary, __half* __restrict__ Y,
             __half* __restrict__ u16) {
  int q = blockIdx.x*256 + threadIdx.x;           // quad id, [0, NPIX/4)
  int b = q >> 16;
  int rem = q & 65535;
  size_t base = (size_t)b*NC*(PLANE>>2) + rem;
  const float4* up = reinterpret_cast<const float4*>(unary);
  uint2* u16p = reinterpret_cast<uint2*>(u16);
  float v[NC][4];
  float mx0=-3e38f,mx1=-3e38f,mx2=-3e38f,mx3=-3e38f;
#pragma unroll
  for (int c=0;c<NC;++c) {
    float4 t = up[base + (size_t)c*(PLANE>>2)];
    if (WU16) {
      uint2 w; w.x=f2h(t.x,t.y); w.y=f2h(t.z,t.w);
      u16p[base + (size_t)c*(PLANE>>2)] = w;
    }
    v[c][0]=t.x; v[c][1]=t.y; v[c][2]=t.z; v[c][3]=t.w;
    mx0=fmaxf(mx0,t.x); mx1=fmaxf(mx1,t.y); mx2=fmaxf(mx2,t.z); mx3=fmaxf(mx3,t.w);
  }
  float s0=0,s1=0,s2=0,s3=0;
#pragma unroll
  for (int c=0;c<NC;++c) {
    float e0=__expf(v[c][0]-mx0), e1=__expf(v[c][1]-mx1);
    float e2=__expf(v[c][2]-mx2), e3=__expf(v[c][3]-mx3);
    v[c][0]=e0; v[c][1]=e1; v[c][2]=e2; v[c][3]=e3;
    s0+=e0; s1+=e1; s2+=e2; s3+=e3;
  }
  float r0=1.f/s0, r1=1.f/s1, r2=1.f/s2, r3=1.f/s3;
  uint2* yp = reinterpret_cast<uint2*>(Y);
#pragma unroll
  for (int c=0;c<NC;++c) {
    uint2 w; w.x=f2h(v[c][0]*r0, v[c][1]*r1); w.y=f2h(v[c][2]*r2, v[c][3]*r3);
    yp[base + (size_t)c*(PLANE>>2)] = w;
  }
}

#define CROW 72            // LDS row stride (halves) == staged cols
#define TROWS 12           // staged rows (8 tile + 4 halo)
#define CTILE (TROWS*CROW) // halves per channel buffer (864)

// ---------------- FAST fused CRF iteration (identity compat) ----------------
// R10: online softmax (T13 defer-max) with fp16 probabilities in LDS.
// R9 post-mortem: no pipe >45% busy -> latency-bound; fp32 logits (43 KB LDS)
// capped occupancy at 12 waves/CU regardless of tile shape. Now: running
// max/sum in 4 scalar regs (scalars never spill; only ARRAYS trip the
// allocator, R4-R7 lesson); store p=exp(l-m)<=e^8 as half2 (21.5 KB).
// Rescale stored p's only when max jumps >8 (rare, predicated LDS RMW).
// Softmax is shift-invariant -> defer-max exact in fp32; fp16 p rel err
// 2^-11 -> output err ~5e-4. LDS 30.1 KB -> 5 blocks/CU = 20 waves/CU.
// Phase 2 collapses to one scale+store pass. General compat -> k_iter_gen.
// KEY INVARIANT: WRITE_SIZE must stay 86016 KiB (no spills).

#define COMPUTE_CHF(c, buf, uu, uf) do { \
    const __half* qrow0_ = (buf) + ty*CROW + lx2; \
    __half2 a0_ = __float2half2_rn(0.f); \
    __half2 a1_ = a0_, a2_ = a0_; \
    float ce0=0.f,ce1=0.f,ce2=0.f,ce3=0.f; \
    _Pragma("unroll") \
    for (int dy=0;dy<5;++dy) { \
      const __half2* qrow = reinterpret_cast<const __half2*>(qrow0_ + dy*CROW); \
      __half2 q0=qrow[0], q1=qrow[1], q2=qrow[2]; \
      a0_ = __hadd2(a0_, q0); a1_ = __hadd2(a1_, q1); a2_ = __hadd2(a2_, q2); \
      if (dy>=1 && dy<=3) { \
        ce0 += __high2float(q0)*ew[dy-1][0]; \
        ce1 += __low2float (q1)*ew[dy-1][1]; \
        ce2 += __high2float(q1)*ew[dy-1][2]; \
        ce3 += __low2float (q2)*ew[dy-1][3]; \
      } \
    } \
    float cs0=__low2float(a0_), cs1=__high2float(a0_); \
    float cs2=__low2float(a1_), cs3=__high2float(a1_); \
    float cs4=__low2float(a2_), cs5=__high2float(a2_); \
    float v0 = cs0+cs1+cs2+cs3+cs4; \
    float v1 = v0 - cs0 + cs5; \
    float w0 = ce0+ce1+ce2; \
    float w1 = ce1+ce2+ce3; \
    float mg0 = csw*v0 + cb0*w0; \
    float mg1 = csw*v1 + cb1*w1; \
    float u0c,u1c; \
    if (U16) { float2 t_=h2f(uu); u0c=t_.x; u1c=t_.y; } \
    else     { u0c=(uf).x; u1c=(uf).y; } \
    float l0_ = u0c - mg0, l1_ = u1c - mg1; \
    float d0_ = l0_ - rmx0, d1_ = l1_ - rmx1; \
    if (d0_ > 8.f || d1_ > 8.f) { \
      float sc0_ = (d0_ > 8.f) ? __expf(-d0_) : 1.f; \
      float sc1_ = (d1_ > 8.f) ? __expf(-d1_) : 1.f; \
      _Pragma("unroll 1") \
      for (int dd=0; dd<(c); ++dd) { \
        float2 pv_ = h2f(psm[dd][tid]); \
        psm[dd][tid] = f2h(pv_.x*sc0_, pv_.y*sc1_); \
      } \
      sr0 *= sc0_; sr1 *= sc1_; \
      if (d0_ > 8.f) { rmx0 = l0_; d0_ = 0.f; } \
      if (d1_ > 8.f) { rmx1 = l1_; d1_ = 0.f; } \
    } \
    float p0_ = __expf(d0_), p1_ = __expf(d1_); \
    sr0 += p0_; sr1 += p1_; \
    psm[(c)][tid] = f2h(p0_, p1_); \
  } while(0)

template<bool U16, bool OUTF32>
__global__ __launch_bounds__(256)
void k_iter_f(const __half* __restrict__ Qin,
              void* __restrict__ Qout,
              const void* __restrict__ uptr,
              const __half* __restrict__ edge16,
              const float* __restrict__ rnorm,
              const float* __restrict__ swp,
              const float* __restrict__ bwp,
              const float* __restrict__ compat,
              const int* __restrict__ flag)
{
  __shared__ __half qbuf[2][2][CTILE];   // 6912 B
  __shared__ __half et[CTILE];           // 1728 B
  __shared__ unsigned int psm[NC][256];  // 21504 B   total 30144 B

  const int fl = flag[0];
  if (!fl) return;                       // general compat handled by k_iter_gen

  const int tid = threadIdx.x;
  const int tx = tid & 31;        // 32 threads across 64 px, 2 px each
  const int ty = tid >> 5;        // 8 rows
  const int x0 = blockIdx.x << 6;
  const int y0 = blockIdx.y << 3;
  const int b  = blockIdx.z;

  // ---- staging slot: 12 rows x 18 uint2 (4 halves) = 216 slots ----
  const int slot = tid;
  const int sr_ = slot / 18;
  const int si = slot - sr_*18;
  const int sy = y0 - 2 + sr_;                // rows y0-2 .. y0+9
  const int sx = x0 - 4 + (si<<2);            // cols x0-4 .. x0+67, step 4
  const bool sact = (slot < 216);
  const bool sval = sact && (sy>=0) && (sy<512) && (sx>=0) && (sx<512);
  const int  goff = (sy<<9) + sx;             // halves into plane (use iff sval)
  const int  loff = sr_*CROW + (si<<2);       // halves into tile

  const int gy  = y0 + ty;
  const int gx  = x0 + (tx<<1);
  const int pix = (gy<<9) | gx;

  // early independent loads (overlap with staging latency)
  const float2 rn = *reinterpret_cast<const float2*>(rnorm + (size_t)b*PLANE + pix);
  const float sw  = fmaxf(swp[0], 0.f);
  const float bw  = fmaxf(bwp[0], 0.f);

  const size_t hbase = (((size_t)b*NC*PLANE) + (size_t)pix) >> 1;  // uint / float2 units
  const size_t ch = PLANE >> 1;

  // ---- prologue: u[0],u[1] + edge tile + ch0/ch1 tiles, one barrier ----
  const __half* qb = Qin + (size_t)b*NC*PLANE;
  unsigned int uc0=0, uc1=0; float2 uf0=make_float2(0.f,0.f), uf1=uf0;
  if (U16) {
    uc0 = reinterpret_cast<const unsigned int*>(uptr)[hbase];
    uc1 = reinterpret_cast<const unsigned int*>(uptr)[hbase + ch];
  } else {
    uf0 = reinterpret_cast<const float2*>(uptr)[hbase];
    uf1 = reinterpret_cast<const float2*>(uptr)[hbase + ch];
  }
  {
    const __half* ep = edge16 + (size_t)b*PLANE;
    uint2 we = make_uint2(0u,0u), w0 = we, w1 = we;
    if (sval) {
      we = *reinterpret_cast<const uint2*>(ep + goff);
      w0 = *reinterpret_cast<const uint2*>(qb + goff);
      w1 = *reinterpret_cast<const uint2*>(qb + PLANE + goff);
    }
    if (sact) {
      *reinterpret_cast<uint2*>(et + loff) = we;
      *reinterpret_cast<uint2*>(qbuf[0][0] + loff) = w0;
      *reinterpret_cast<uint2*>(qbuf[0][1] + loff) = w1;
    }
  }
  __syncthreads();

  const float csw = sw * 0.04f;          // sw/25
  const float b9  = bw * (1.f/9.f);      // bw/9
  const float cb0 = b9*rn.x, cb1 = b9*rn.y;

  const int lx2 = (tx<<1) + 2;           // LDS col of gx-2 (staged region shift)

  // hoist edge window into registers once (channel-invariant)
  float ew[3][4];
#pragma unroll
  for (int dy=0;dy<3;++dy) {
    const unsigned int* erow = reinterpret_cast<const unsigned int*>(et + (ty+1+dy)*CROW + lx2);
    float2 e0 = h2f(erow[0]);
    float2 e1 = h2f(erow[1]);
    float2 e2 = h2f(erow[2]);
    ew[dy][0]=e0.y; ew[dy][1]=e1.x; ew[dy][2]=e1.y; ew[dy][3]=e2.x;
  }

  // ---- pipelined pair loop with online softmax (scalars only) ----
  float rmx0=-3e38f, rmx1=-3e38f;   // running max (epoch shared by all stored p)
  float sr0=0.f, sr1=0.f;           // running sums

#pragma unroll
  for (int cp=0; cp<11; ++cp) {
    const int c0 = 2*cp, c1 = 2*cp+1;

    // prefetch next pair's tiles + unary (hidden under compute)
    uint2 wn0 = make_uint2(0u,0u), wn1 = wn0;
    unsigned int un0=0, un1=0; float2 unf0=make_float2(0.f,0.f), unf1=unf0;
    if (c0+2 < NC) {
      if (sval) wn0 = *reinterpret_cast<const uint2*>(qb + (size_t)(c0+2)*PLANE + goff);
      if (U16) un0 = reinterpret_cast<const unsigned int*>(uptr)[hbase + (size_t)(c0+2)*ch];
      else     unf0 = reinterpret_cast<const float2*>(uptr)[hbase + (size_t)(c0+2)*ch];
    }
    if (c1+2 < NC) {
      if (sval) wn1 = *reinterpret_cast<const uint2*>(qb + (size_t)(c1+2)*PLANE + goff);
      if (U16) un1 = reinterpret_cast<const unsigned int*>(uptr)[hbase + (size_t)(c1+2)*ch];
      else     unf1 = reinterpret_cast<const float2*>(uptr)[hbase + (size_t)(c1+2)*ch];
    }

    COMPUTE_CHF(c0, qbuf[cp&1][0], uc0, uf0);
    if (c1 < NC) COMPUTE_CHF(c1, qbuf[cp&1][1], uc1, uf1);

    if (c0+2 < NC) {
      if (sact) {
        *reinterpret_cast<uint2*>(qbuf[(cp+1)&1][0] + loff) = wn0;
        if (c1+2 < NC) *reinterpret_cast<uint2*>(qbuf[(cp+1)&1][1] + loff) = wn1;
      }
      __syncthreads();
    }
    uc0=un0; uc1=un1; uf0=unf0; uf1=unf1;
  }

  // ---- phase 2: single scale+store pass ----
  float r0 = 1.f/sr0, r1 = 1.f/sr1;
#pragma unroll
  for (int c=0;c<NC;++c) {
    float2 pv = h2f(psm[c][tid]);
    float o0 = pv.x*r0, o1 = pv.y*r1;
    if (OUTF32) {
      reinterpret_cast<float2*>(Qout)[hbase + (size_t)c*ch] = make_float2(o0,o1);
    } else {
      reinterpret_cast<unsigned int*>(Qout)[hbase + (size_t)c*ch] = f2h(o0,o1);
    }
  }
}

// ---------------- GENERAL fused CRF iteration (compat != identity) ----------------
// R9 body verbatim + early exit when flag==1 (fast kernel handles that case).
// Cold path in practice; keeps exact fp32 logits in LDS (51.6 KB).

#define LOAD_U2(c, u0,u1) \
  float u0,u1; \
  if (U16) { unsigned int w_ = reinterpret_cast<const unsigned int*>(uptr)[hbase + (size_t)(c)*ch]; \
    float2 t_=h2f(w_); u0=t_.x; u1=t_.y; } \
  else { float2 v_ = reinterpret_cast<const float2*>(uptr)[hbase + (size_t)(c)*ch]; \
    u0=v_.x; u1=v_.y; }

#define COMPUTE_CHG(c, buf, uu, uf) do { \
    const __half* qrow0_ = (buf) + ty*CROW + lx2; \
    __half2 a0_ = __float2half2_rn(0.f); \
    __half2 a1_ = a0_, a2_ = a0_; \
    float ce0=0.f,ce1=0.f,ce2=0.f,ce3=0.f; \
    _Pragma("unroll") \
    for (int dy=0;dy<5;++dy) { \
      const __half2* qrow = reinterpret_cast<const __half2*>(qrow0_ + dy*CROW); \
      __half2 q0=qrow[0], q1=qrow[1], q2=qrow[2]; \
      a0_ = __hadd2(a0_, q0); a1_ = __hadd2(a1_, q1); a2_ = __hadd2(a2_, q2); \
      if (dy>=1 && dy<=3) { \
        ce0 += __high2float(q0)*ew[dy-1][0]; \
        ce1 += __low2float (q1)*ew[dy-1][1]; \
        ce2 += __high2float(q1)*ew[dy-1][2]; \
        ce3 += __low2float (q2)*ew[dy-1][3]; \
      } \
    } \
    float cs0=__low2float(a0_), cs1=__high2float(a0_); \
    float cs2=__low2float(a1_), cs3=__high2float(a1_); \
    float cs4=__low2float(a2_), cs5=__high2float(a2_); \
    float v0 = cs0+cs1+cs2+cs3+cs4; \
    float v1 = v0 - cs0 + cs5; \
    float w0 = ce0+ce1+ce2; \
    float w1 = ce1+ce2+ce3; \
    float m0 = csw*v0 + cb0*w0; \
    float m1 = csw*v1 + cb1*w1; \
    lsm[c][tid] = make_float2(m0, m1); \
  } while(0)

template<bool U16, bool OUTF32>
__global__ __launch_bounds__(256)
void k_iter_gen(const __half* __restrict__ Qin,
                void* __restrict__ Qout,
                const void* __restrict__ uptr,
                const __half* __restrict__ edge16,
                const float* __restrict__ rnorm,
                const float* __restrict__ swp,
                const float* __restrict__ bwp,
                const float* __restrict__ compat,
                const int* __restrict__ flag)
{
  __shared__ __half qbuf[2][2][CTILE]; // 6912 B
  __shared__ __half et[CTILE];         // 1728 B
  __shared__ float2 lsm[NC][256];      // 43008 B

  const int fl = flag[0];
  if (fl) return;                      // identity handled by k_iter_f

  const int tid = threadIdx.x;
  const int tx = tid & 31;
  const int ty = tid >> 5;
  const int x0 = blockIdx.x << 6;
  const int y0 = blockIdx.y << 3;
  const int b  = blockIdx.z;

  const int slot = tid;
  const int sr_ = slot / 18;
  const int si = slot - sr_*18;
  const int sy = y0 - 2 + sr_;
  const int sx = x0 - 4 + (si<<2);
  const bool sact = (slot < 216);
  const bool sval = sact && (sy>=0) && (sy<512) && (sx>=0) && (sx<512);
  const int  goff = (sy<<9) + sx;
  const int  loff = sr_*CROW + (si<<2);

  const int gy  = y0 + ty;
  const int gx  = x0 + (tx<<1);
  const int pix = (gy<<9) | gx;

  const float2 rn = *reinterpret_cast<const float2*>(rnorm + (size_t)b*PLANE + pix);
  const float sw  = fmaxf(swp[0], 0.f);
  const float bw  = fmaxf(bwp[0], 0.f);

  const size_t hbase = (((size_t)b*NC*PLANE) + (size_t)pix) >> 1;
  const size_t ch = PLANE >> 1;

  const __half* qb = Qin + (size_t)b*NC*PLANE;
  {
    const __half* ep = edge16 + (size_t)b*PLANE;
    uint2 we = make_uint2(0u,0u), w0 = we, w1 = we;
    if (sval) {
      we = *reinterpret_cast<const uint2*>(ep + goff);
      w0 = *reinterpret_cast<const uint2*>(qb + goff);
      w1 = *reinterpret_cast<const uint2*>(qb + PLANE + goff);
    }
    if (sact) {
      *reinterpret_cast<uint2*>(et + loff) = we;
      *reinterpret_cast<uint2*>(qbuf[0][0] + loff) = w0;
      *reinterpret_cast<uint2*>(qbuf[0][1] + loff) = w1;
    }
  }
  __syncthreads();

  const float csw = sw * 0.04f;
  const float b9  = bw * (1.f/9.f);
  const float cb0 = b9*rn.x, cb1 = b9*rn.y;

  const int lx2 = (tx<<1) + 2;

  float ew[3][4];
#pragma unroll
  for (int dy=0;dy<3;++dy) {
    const unsigned int* erow = reinterpret_cast<const unsigned int*>(et + (ty+1+dy)*CROW + lx2);
    float2 e0 = h2f(erow[0]);
    float2 e1 = h2f(erow[1]);
    float2 e2 = h2f(erow[2]);
    ew[dy][0]=e0.y; ew[dy][1]=e1.x; ew[dy][2]=e1.y; ew[dy][3]=e2.x;
  }

#pragma unroll
  for (int cp=0; cp<11; ++cp) {
    const int c0 = 2*cp, c1 = 2*cp+1;
    uint2 wn0 = make_uint2(0u,0u), wn1 = wn0;
    if (c0+2 < NC && sval) wn0 = *reinterpret_cast<const uint2*>(qb + (size_t)(c0+2)*PLANE + goff);
    if (c1+2 < NC && sval) wn1 = *reinterpret_cast<const uint2*>(qb + (size_t)(c1+2)*PLANE + goff);

    COMPUTE_CHG(c0, qbuf[cp&1][0], 0, 0);
    if (c1 < NC) COMPUTE_CHG(c1, qbuf[cp&1][1], 0, 0);

    if (c0+2 < NC) {
      if (sact) {
        *reinterpret_cast<uint2*>(qbuf[(cp+1)&1][0] + loff) = wn0;
        if (c1+2 < NC) *reinterpret_cast<uint2*>(qbuf[(cp+1)&1][1] + loff) = wn1;
      }
      __syncthreads();
    }
  }

  // general compat: messages in LDS, recompute logits per pass
  float mxa=-3e38f, mxb=-3e38f;
#pragma unroll 1
  for (int c=0;c<NC;++c) {
    float a0=0.f,a1=0.f;
#pragma unroll
    for (int d=0;d<NC;++d) { float cf=compat[c*NC+d]; float2 lv=lsm[d][tid]; a0+=cf*lv.x; a1+=cf*lv.y; }
    LOAD_U2(c, u0,u1)
    mxa=fmaxf(mxa,u0-a0); mxb=fmaxf(mxb,u1-a1);
  }
  float s0=0.f,s1=0.f;
#pragma unroll 1
  for (int c=0;c<NC;++c) {
    float a0=0.f,a1=0.f;
#pragma unroll
    for (int d=0;d<NC;++d) { float cf=compat[c*NC+d]; float2 lv=lsm[d][tid]; a0+=cf*lv.x; a1+=cf*lv.y; }
    LOAD_U2(c, u0,u1)
    s0+=__expf(u0-a0-mxa); s1+=__expf(u1-a1-mxb);
  }
  float r0=1.f/s0, r1=1.f/s1;
#pragma unroll 1
  for (int c=0;c<NC;++c) {
    float a0=0.f,a1=0.f;
#pragma unroll
    for (int d=0;d<NC;++d) { float cf=compat[c*NC+d]; float2 lv=lsm[d][tid]; a0+=cf*lv.x; a1+=cf*lv.y; }
    LOAD_U2(c, u0,u1)
    float o0=__expf(u0-a0-mxa)*r0, o1=__expf(u1-a1-mxb)*r1;
    if (OUTF32) {
      reinterpret_cast<float2*>(Qout)[hbase + (size_t)c*ch] = make_float2(o0,o1);
    } else {
      reinterpret_cast<unsigned int*>(Qout)[hbase + (size_t)c*ch] = f2h(o0,o1);
    }
  }
}

extern "C" void kernel_launch(void* const* d_in, const int* in_sizes, int n_in,
                              void* d_out, int out_size, void* d_ws, size_t ws_size,
                              hipStream_t stream)
{
  const float* unary  = (const float*)d_in[0];
  const float* image  = (const float*)d_in[1];
  const float* compat = (const float*)d_in[2];
  const float* swp    = (const float*)d_in[3];
  const float* bwp    = (const float*)d_in[4];

  // ws layout (bytes): X fp16 Q buffer | edge16 | rnorm | flag | (opt) u16
  char* ws = (char*)d_ws;
  __half* X      = (__half*)(ws + 0);            // 88,080,384 B
  __half* edge16 = (__half*)(ws + 88080384);     //  4,194,304 B
  float*  rnorm  = (float*) (ws + 92274688);     //  8,388,608 B
  int*    flag   = (int*)   (ws + 100663296);    //        256 B
  __half* u16    = (__half*)(ws + 100663552);    // 88,080,384 B (optional)
  if (ws_size < (size_t)100663552) return;       // cannot run without scratch
  const bool use_u16 = (ws_size >= (size_t)188743936);

  __half* Y  = (__half*)d_out;   // d_out doubles as fp16 scratch during iters
  float* out = (float*)d_out;

  k_edge   <<<dim3(8192), dim3(256), 0, stream>>>(image, edge16);
  k_rnorm  <<<dim3(8192), dim3(256), 0, stream>>>(edge16, rnorm);
  k_flag   <<<dim3(1),    dim3(256), 0, stream>>>(compat, flag);
  if (use_u16) k_prep0<true ><<<dim3(2048), dim3(256), 0, stream>>>(unary, Y, u16);
  else         k_prep0<false><<<dim3(2048), dim3(256), 0, stream>>>(unary, Y, u16);

  const void* up = use_u16 ? (const void*)u16 : (const void*)unary;
  dim3 gi(8, 64, NB), bi(256);
  // Q0 -> Y(d_out,fp16); odd iters Y->X; even iters X->Y; iter10 X -> d_out fp32
  for (int it = 1; it <= 10; ++it) {
    const __half* qin = (it & 1) ? Y : X;
    if (it == 10) {
      if (use_u16) {
        k_iter_f  <true , true ><<<gi,bi,0,stream>>>(qin,(void*)out,up,edge16,rnorm,swp,bwp,compat,flag);
        k_iter_gen<true , true ><<<gi,bi,0,stream>>>(qin,(void*)out,up,edge16,rnorm,swp,bwp,compat,flag);
      } else {
        k_iter_f  <false, true ><<<gi,bi,0,stream>>>(qin,(void*)out,up,edge16,rnorm,swp,bwp,compat,flag);
        k_iter_gen<false, true ><<<gi,bi,0,stream>>>(qin,(void*)out,up,edge16,rnorm,swp,bwp,compat,flag);
      }
    } else {
      void* qout = (it & 1) ? (void*)X : (void*)Y;
      if (use_u16) {
        k_iter_f  <true , false><<<gi,bi,0,stream>>>(qin,qout,up,edge16,rnorm,swp,bwp,compat,flag);
        k_iter_gen<true , false><<<gi,bi,0,stream>>>(qin,qout,up,edge16,rnorm,swp,bwp,compat,flag);
      } else {
        k_iter_f  <false, false><<<gi,bi,0,stream>>>(qin,qout,up,edge16,rnorm,swp,bwp,compat,flag);
        k_iter_gen<false, false><<<gi,bi,0,stream>>>(qin,qout,up,edge16,rnorm,swp,bwp,compat,flag);
      }
    }
  }
}